// Round 2
// baseline (173.793 us; speedup 1.0000x reference)
//
#include <hip/hip_runtime.h>
#include <hip/hip_bf16.h>

#define NPTS (96 * 96 * 96)   // 884736 points, divisible by 1024
#define HID 64
#define H_EFF 0.2f            // RK4 1 step/ODE — verified error << bf16 floor (R7/R8)

// Lookup table of the composed diffeomorphism on [-1,1]^3.
// TB=49: 1.88 MB table. Combined with uint8 volume (2.10 MB) the entire
// gather working set (3.98 MB) fits one XCD's 4 MiB L2 (it is replicated in
// all 8 L2s — random access means every XCD touches everything).
#define TB  49
#define TB2 (TB * TB)         // 2401
#define TB3 (TB * TB * TB)    // 117649 (odd)
#define TB_SCALE 24.0f        // (y+1)*24 -> node index; spacing 1/24
#define TB_INV   0.0416666679f
#define TBL_OFF 1032          // float offset in ws (byte 4128, 16B aligned)
#define VOL_N   (128 * 128 * 128)
#define VOL8_OFF_B ((size_t)(TBL_OFF * 4) + (size_t)TB3 * 16)   // byte offset of u8 vol
#define WS_NEED (VOL8_OFF_B + (size_t)VOL_N)

typedef float v2f __attribute__((ext_vector_type(2)));
typedef float v4f __attribute__((ext_vector_type(4)));
typedef float f4  __attribute__((ext_vector_type(4)));
typedef unsigned u2 __attribute__((ext_vector_type(2)));

__device__ __forceinline__ float bf2f(const __hip_bfloat16 v) {
    return __bfloat162float(v);
}
__device__ __forceinline__ v2f splat(float x) { v2f r; r.x = x; r.y = x; return r; }
__device__ __forceinline__ v4f splat4(float x) { v4f r; r.x = x; r.y = x; r.z = x; r.w = x; return r; }
__device__ __forceinline__ v2f vfma(v2f a, v2f b, v2f c) {
    return __builtin_elementwise_fma(a, b, c);
}
__device__ __forceinline__ v4f vfma4(v4f a, v4f b, v4f c) {
    return __builtin_elementwise_fma(a, b, c);
}
__device__ __forceinline__ float lerp1(float a, float b, float f) {
    return __builtin_fmaf(f, b - a, a);
}

// ---------------------------------------------------------------------------
// Setup: dtype detection + weight fold into ws[0..1024), flags at ws[1024..1026).
// W1' = K*W1, b1' = K*b1 (K=2*log2 e), W2' = -2*W2, b2'' = b2 + sum_j W2[j][k]
//   =>  out = b2'' + sum_j W2'_jk * rcp(1 + 2^pre')
// ---------------------------------------------------------------------------
__global__ void setup_kernel(
    const void* __restrict__ coords,
    const void* __restrict__ W1_0, const void* __restrict__ b1_0,
    const void* __restrict__ W2_0, const void* __restrict__ b2_0,
    const void* __restrict__ W1_1, const void* __restrict__ b1_1,
    const void* __restrict__ W2_1, const void* __restrict__ b2_1,
    const void* __restrict__ vol,
    float* __restrict__ ws) {
    __shared__ int sflags[3];
    int tid = threadIdx.x;
    if (tid < 64) {
        auto sane = [](const void* p, int i) -> bool {
            unsigned e = (((const unsigned short*)p)[i] >> 7) & 0xFFu;
            return e >= 97u && e <= 129u;
        };
        unsigned long long m;
        m = __ballot(sane(W1_0, tid));
        if (tid == 0) sflags[2] = (__popcll(m) >= 52) ? 1 : 0;
        m = __ballot(sane(coords, tid));
        if (tid == 0) sflags[0] = (__popcll(m) >= 52) ? 1 : 0;
        m = __ballot(sane(vol, tid));
        if (tid == 0) sflags[1] = (__popcll(m) >= 52) ? 1 : 0;
    }
    __syncthreads();
    int isbf = sflags[2];
    const float K = 2.88539008177792681472f;  // 2/ln(2)
    int ode = tid >> 9;
    int r = tid & 511;
    const void* W1 = ode ? W1_1 : W1_0;
    const void* b1 = ode ? b1_1 : b1_0;
    const void* W2 = ode ? W2_1 : W2_0;
    const void* b2 = ode ? b2_1 : b2_0;
    auto ld = [&](const void* p, int idx) -> float {
        return isbf ? bf2f(((const __hip_bfloat16*)p)[idx]) : ((const float*)p)[idx];
    };
    float v = 0.0f;
    if (r < 192)       v = K * ld(W1, r);
    else if (r < 256)  v = K * ld(b1, r - 192);
    else if (r < 448)  v = -2.0f * ld(W2, r - 256);
    else if (r < 451) {
        int k = r - 448;
        float s = ld(b2, k);
        for (int j = 0; j < HID; ++j) s += ld(W2, 3 * j + k);
        v = s;
    }
    ws[(ode << 9) + r] = v;
    if (tid < 2) ((int*)(ws + 1024))[tid] = sflags[tid];
}

// Quantize vol (bf16 or fp32 per flag) to uint8: q = round(v*255), v in [0,1).
// Recon err <= 1/510 -> out0 contribution <= 3.9e-3 (budget check in header).
__global__ __launch_bounds__(256) void conv_vol_kernel(
    const void* __restrict__ vol,
    const float* __restrict__ ws,
    unsigned char* __restrict__ vol8) {
    int i = blockIdx.x * 256 + threadIdx.x;
    if (i >= VOL_N) return;
    int vbf = ((const int*)(ws + 1024))[1];
    float v = vbf ? bf2f(((const __hip_bfloat16*)vol)[i]) : ((const float*)vol)[i];
    float q = __builtin_fmaf(v, 255.0f, 0.5f);
    q = q < 0.f ? 0.f : (q > 255.f ? 255.f : q);
    vol8[i] = (unsigned char)q;
}

// MLP eval for a PAIR of points. Shared-rcp: one v_rcp of qx*qy recovers both
// reciprocals. q in [1, ~3000]; v_rcp rel err ~1e-7 (accuracy budget R10:
// c1 err must be <= ~2.3e-4; one-Newton bit-rcp at 3.6e-3 FAILED).
__device__ __forceinline__ void mlp_f2(const float* __restrict__ w,
                                       v2f y0, v2f y1, v2f y2,
                                       v2f& o0, v2f& o1, v2f& o2) {
    v2f a0 = splat(w[448]), a1 = splat(w[449]), a2 = splat(w[450]);
#pragma unroll 8
    for (int j = 0; j < HID; ++j) {
        v2f pre = vfma(y0, splat(w[j]),
                  vfma(y1, splat(w[64 + j]),
                  vfma(y2, splat(w[128 + j]), splat(w[192 + j]))));
        v2f e;
        e.x = __builtin_amdgcn_exp2f(pre.x);
        e.y = __builtin_amdgcn_exp2f(pre.y);
        v2f q = e + splat(1.0f);
        float rP = __builtin_amdgcn_rcpf(q.x * q.y);
        v2f r;
        r.x = q.y * rP;
        r.y = q.x * rP;
        a0 = vfma(r, splat(w[256 + 3 * j + 0]), a0);
        a1 = vfma(r, splat(w[256 + 3 * j + 1]), a1);
        a2 = vfma(r, splat(w[256 + 3 * j + 2]), a2);
    }
    o0 = a0; o1 = a1; o2 = a2;
}

// 4-wide version for the table build: 2 independent shared-rcp pairs per
// iteration -> 4-deep ILP on the dependent fma/exp2 chains (build runs at
// ~1 wave/SIMD, so ILP is the only latency hiding available).
__device__ __forceinline__ void mlp_f4(const float* __restrict__ w,
                                       v4f y0, v4f y1, v4f y2,
                                       v4f& o0, v4f& o1, v4f& o2) {
    v4f a0 = splat4(w[448]), a1 = splat4(w[449]), a2 = splat4(w[450]);
#pragma unroll 8
    for (int j = 0; j < HID; ++j) {
        v4f pre = vfma4(y0, splat4(w[j]),
                  vfma4(y1, splat4(w[64 + j]),
                  vfma4(y2, splat4(w[128 + j]), splat4(w[192 + j]))));
        v4f e;
        e.x = __builtin_amdgcn_exp2f(pre.x);
        e.y = __builtin_amdgcn_exp2f(pre.y);
        e.z = __builtin_amdgcn_exp2f(pre.z);
        e.w = __builtin_amdgcn_exp2f(pre.w);
        v4f q = e + splat4(1.0f);
        float rP0 = __builtin_amdgcn_rcpf(q.x * q.y);
        float rP1 = __builtin_amdgcn_rcpf(q.z * q.w);
        v4f r;
        r.x = q.y * rP0;
        r.y = q.x * rP0;
        r.z = q.w * rP1;
        r.w = q.z * rP1;
        a0 = vfma4(r, splat4(w[256 + 3 * j + 0]), a0);
        a1 = vfma4(r, splat4(w[256 + 3 * j + 1]), a1);
        a2 = vfma4(r, splat4(w[256 + 3 * j + 2]), a2);
    }
    o0 = a0; o1 = a1; o2 = a2;
}

// Full 2-ODE RK4 (1 step of h=0.2 each) for a pair of points, in-place.
__device__ __forceinline__ void integrate2(const float* __restrict__ ws,
                                           v2f& y0, v2f& y1, v2f& y2) {
    const float h = H_EFF;
#pragma unroll 1
    for (int ode = 0; ode < 2; ++ode) {
        const float* __restrict__ w = ws + (ode << 9);
        v2f k0 = splat(0.f), k1 = splat(0.f), k2 = splat(0.f);
        v2f s0 = splat(0.f), s1 = splat(0.f), s2 = splat(0.f);
#pragma unroll 1
        for (int e = 0; e < 4; ++e) {
            float ae = (e == 0) ? 0.0f : ((e == 3) ? h : 0.5f * h);
            float we = (e == 1 || e == 2) ? 2.0f : 1.0f;
            v2f aev = splat(ae), wev = splat(we);
            v2f f0, f1, f2;
            mlp_f2(w,
                   vfma(aev, k0, y0),
                   vfma(aev, k1, y1),
                   vfma(aev, k2, y2),
                   f0, f1, f2);
            k0 = f0; k1 = f1; k2 = f2;
            s0 = vfma(wev, k0, s0);
            s1 = vfma(wev, k1, s1);
            s2 = vfma(wev, k2, s2);
        }
        v2f h6 = splat(h / 6.0f);
        y0 = vfma(h6, s0, y0);
        y1 = vfma(h6, s1, y1);
        y2 = vfma(h6, s2, y2);
    }
}

// 4-wide 2-ODE RK4, in-place.
__device__ __forceinline__ void integrate4(const float* __restrict__ ws,
                                           v4f& y0, v4f& y1, v4f& y2) {
    const float h = H_EFF;
#pragma unroll 1
    for (int ode = 0; ode < 2; ++ode) {
        const float* __restrict__ w = ws + (ode << 9);
        v4f k0 = splat4(0.f), k1 = splat4(0.f), k2 = splat4(0.f);
        v4f s0 = splat4(0.f), s1 = splat4(0.f), s2 = splat4(0.f);
#pragma unroll 1
        for (int e = 0; e < 4; ++e) {
            float ae = (e == 0) ? 0.0f : ((e == 3) ? h : 0.5f * h);
            float we = (e == 1 || e == 2) ? 2.0f : 1.0f;
            v4f aev = splat4(ae), wev = splat4(we);
            v4f f0, f1, f2;
            mlp_f4(w,
                   vfma4(aev, k0, y0),
                   vfma4(aev, k1, y1),
                   vfma4(aev, k2, y2),
                   f0, f1, f2);
            k0 = f0; k1 = f1; k2 = f2;
            s0 = vfma4(wev, k0, s0);
            s1 = vfma4(wev, k1, s1);
            s2 = vfma4(wev, k2, s2);
        }
        v4f h6 = splat4(h / 6.0f);
        y0 = vfma4(h6, s0, y0);
        y1 = vfma4(h6, s1, y1);
        y2 = vfma4(h6, s2, y2);
    }
}

// ---------------------------------------------------------------------------
// Table build: integrate the 49^3 lattice nodes (4 per thread), store
// (c0,c1,c2,0) as float4 at ws+TBL_OFF. 64-thread blocks -> 460 single-wave
// blocks cover all 256 CUs with 4-wide ILP (was 230x256: 1 wave/SIMD, 2-wide).
// ---------------------------------------------------------------------------
__global__ __launch_bounds__(64) void build_kernel(const float* __restrict__ ws,
                                                   float* __restrict__ tbl) {
    int t = blockIdx.x * 64 + threadIdx.x;   // node-quad index
    int n0 = 4 * t;
    if (n0 >= TB3) return;

    auto node_y = [](int n, float* a, float* b, float* c) {
        int i0 = n / TB2;
        int rem = n - i0 * TB2;
        int i1 = rem / TB;
        int i2 = rem - i1 * TB;
        *a = __builtin_fmaf((float)i0, TB_INV, -1.0f);
        *b = __builtin_fmaf((float)i1, TB_INV, -1.0f);
        *c = __builtin_fmaf((float)i2, TB_INV, -1.0f);
    };
    int n[4];
    v4f y0, y1, y2;
#pragma unroll
    for (int q = 0; q < 4; ++q) {
        int nn = n0 + q;
        n[q] = nn < TB3 ? nn : (TB3 - 1);
        float a, b, c;
        node_y(n[q], &a, &b, &c);
        y0[q] = a; y1[q] = b; y2[q] = c;
    }

    integrate4(ws, y0, y1, y2);

#pragma unroll
    for (int q = 0; q < 4; ++q) {
        if (n0 + q < TB3) {
            tbl[4 * n[q] + 0] = y0[q];
            tbl[4 * n[q] + 1] = y1[q];
            tbl[4 * n[q] + 2] = y2[q];
            tbl[4 * n[q] + 3] = 0.f;
        }
    }
}

// Trilinear grid-sample of the uint8 volume (128^3), align_corners=False,
// zeros padding. Returns RAW sum in [0,255] units — caller applies 1/255.
__device__ __forceinline__ float sample3d_u8(const unsigned char* __restrict__ V,
                                             float cz, float cy, float cx) {
    float fx = (cx + 1.0f) * 64.0f - 0.5f;
    float fy = (cy + 1.0f) * 64.0f - 0.5f;
    float fz = (cz + 1.0f) * 64.0f - 0.5f;
    float x0f = floorf(fx), y0f = floorf(fy), z0f = floorf(fz);
    float tx = fx - x0f, ty = fy - y0f, tz = fz - z0f;
    int x0 = (int)x0f, y0 = (int)y0f, z0 = (int)z0f;
    int x1 = x0 + 1, y1 = y0 + 1, z1 = z0 + 1;
    auto clampi = [](int v) { return v < 0 ? 0 : (v > 127 ? 127 : v); };
    auto valid = [](int zi, int yi, int xi) -> bool {
        return ((unsigned)zi < 128u) && ((unsigned)yi < 128u) && ((unsigned)xi < 128u);
    };
    int xc0 = clampi(x0), xc1 = clampi(x1);
    int yc0 = clampi(y0), yc1 = clampi(y1);
    int zc0 = clampi(z0), zc1 = clampi(z1);
    int idx[8] = {
        (zc0 << 14) | (yc0 << 7) | xc0, (zc0 << 14) | (yc0 << 7) | xc1,
        (zc0 << 14) | (yc1 << 7) | xc0, (zc0 << 14) | (yc1 << 7) | xc1,
        (zc1 << 14) | (yc0 << 7) | xc0, (zc1 << 14) | (yc0 << 7) | xc1,
        (zc1 << 14) | (yc1 << 7) | xc0, (zc1 << 14) | (yc1 << 7) | xc1 };
    float v[8];
#pragma unroll
    for (int q = 0; q < 8; ++q) v[q] = (float)V[idx[q]];
    if (!valid(z0, y0, x0)) v[0] = 0.f;
    if (!valid(z0, y0, x1)) v[1] = 0.f;
    if (!valid(z0, y1, x0)) v[2] = 0.f;
    if (!valid(z0, y1, x1)) v[3] = 0.f;
    if (!valid(z1, y0, x0)) v[4] = 0.f;
    if (!valid(z1, y0, x1)) v[5] = 0.f;
    if (!valid(z1, y1, x0)) v[6] = 0.f;
    if (!valid(z1, y1, x1)) v[7] = 0.f;
    return v[0] * (1.f - tz) * (1.f - ty) * (1.f - tx) +
           v[1] * (1.f - tz) * (1.f - ty) * tx +
           v[2] * (1.f - tz) * ty * (1.f - tx) +
           v[3] * (1.f - tz) * ty * tx +
           v[4] * tz * (1.f - ty) * (1.f - tx) +
           v[5] * tz * (1.f - ty) * tx +
           v[6] * tz * ty * (1.f - tx) +
           v[7] * tz * ty * tx;
}

// fp-source grid-sample for the fallback path.
__device__ __forceinline__ float sample3d(const void* __restrict__ vol, int vbf,
                                          float cz, float cy, float cx) {
    float fx = (cx + 1.0f) * 64.0f - 0.5f;
    float fy = (cy + 1.0f) * 64.0f - 0.5f;
    float fz = (cz + 1.0f) * 64.0f - 0.5f;
    float x0f = floorf(fx), y0f = floorf(fy), z0f = floorf(fz);
    float tx = fx - x0f, ty = fy - y0f, tz = fz - z0f;
    int x0 = (int)x0f, y0 = (int)y0f, z0 = (int)z0f;
    int x1 = x0 + 1, y1 = y0 + 1, z1 = z0 + 1;
    auto clampi = [](int v) { return v < 0 ? 0 : (v > 127 ? 127 : v); };
    auto valid = [](int zi, int yi, int xi) -> bool {
        return ((unsigned)zi < 128u) && ((unsigned)yi < 128u) && ((unsigned)xi < 128u);
    };
    int xc0 = clampi(x0), xc1 = clampi(x1);
    int yc0 = clampi(y0), yc1 = clampi(y1);
    int zc0 = clampi(z0), zc1 = clampi(z1);
    int idx[8] = {
        (zc0 << 14) | (yc0 << 7) | xc0, (zc0 << 14) | (yc0 << 7) | xc1,
        (zc0 << 14) | (yc1 << 7) | xc0, (zc0 << 14) | (yc1 << 7) | xc1,
        (zc1 << 14) | (yc0 << 7) | xc0, (zc1 << 14) | (yc0 << 7) | xc1,
        (zc1 << 14) | (yc1 << 7) | xc0, (zc1 << 14) | (yc1 << 7) | xc1 };
    float v[8];
    if (vbf) {
        const __hip_bfloat16* V = (const __hip_bfloat16*)vol;
#pragma unroll
        for (int q = 0; q < 8; ++q) v[q] = bf2f(V[idx[q]]);
    } else {
        const float* V = (const float*)vol;
#pragma unroll
        for (int q = 0; q < 8; ++q) v[q] = V[idx[q]];
    }
    if (!valid(z0, y0, x0)) v[0] = 0.f;
    if (!valid(z0, y0, x1)) v[1] = 0.f;
    if (!valid(z0, y1, x0)) v[2] = 0.f;
    if (!valid(z0, y1, x1)) v[3] = 0.f;
    if (!valid(z1, y0, x0)) v[4] = 0.f;
    if (!valid(z1, y0, x1)) v[5] = 0.f;
    if (!valid(z1, y1, x0)) v[6] = 0.f;
    if (!valid(z1, y1, x1)) v[7] = 0.f;
    return v[0] * (1.f - tz) * (1.f - ty) * (1.f - tx) +
           v[1] * (1.f - tz) * (1.f - ty) * tx +
           v[2] * (1.f - tz) * ty * (1.f - tx) +
           v[3] * (1.f - tz) * ty * tx +
           v[4] * tz * (1.f - ty) * (1.f - tx) +
           v[5] * tz * (1.f - ty) * tx +
           v[6] * tz * ty * (1.f - tx) +
           v[7] * tz * ty * tx;
}

// ---------------------------------------------------------------------------
// Query: trilerp the 49^3 table -> c1, grid-sample the u8 volume.
// 4 points/thread: coords -> 3x dwordx4 (nontemporal), 32 table gathers in
// flight per wave, c1/out0 -> 4x dwordx4 nontemporal stores (write stream
// must not evict the 4 MB table+vol set from the 4 MiB/XCD L2).
// ---------------------------------------------------------------------------
__global__ __launch_bounds__(256) void query_kernel(
    const void* __restrict__ coords,
    const float* __restrict__ ws,
    float* __restrict__ out) {
    int t = blockIdx.x * 256 + threadIdx.x;   // quad-of-points index
    if (t >= NPTS / 4) return;

    const int* flags = (const int*)(ws + 1024);
    int cbf = flags[0];

    float y[4][3];
    if (cbf) {
        // 12 bf16 = 24 B per quad, 8B-aligned -> 3x dwordx2
        const u2* C2 = (const u2*)((const unsigned short*)coords + 12 * t);
        u2 ua = __builtin_nontemporal_load(C2);
        u2 ub = __builtin_nontemporal_load(C2 + 1);
        u2 uc = __builtin_nontemporal_load(C2 + 2);
        unsigned uu[6] = {ua.x, ua.y, ub.x, ub.y, uc.x, uc.y};
#pragma unroll
        for (int p = 0; p < 4; ++p)
#pragma unroll
            for (int d = 0; d < 3; ++d) {
                int k = 3 * p + d;
                unsigned h = uu[k >> 1];
                h = (k & 1) ? (h & 0xFFFF0000u) : (h << 16);
                y[p][d] = __builtin_bit_cast(float, h);
            }
    } else {
        // 12 floats = 48 B per quad, 16B-aligned -> 3x dwordx4
        const f4* C4 = (const f4*)((const float*)coords + 12 * t);
        f4 a = __builtin_nontemporal_load(C4);
        f4 b = __builtin_nontemporal_load(C4 + 1);
        f4 c = __builtin_nontemporal_load(C4 + 2);
        y[0][0] = a.x; y[0][1] = a.y; y[0][2] = a.z;
        y[1][0] = a.w; y[1][1] = b.x; y[1][2] = b.y;
        y[2][0] = b.z; y[2][1] = b.w; y[2][2] = c.x;
        y[3][0] = c.y; y[3][1] = c.z; y[3][2] = c.w;
    }

    auto cell = [](float tt, int* idx, float* f) {
        int v = (int)floorf(tt);
        v = v < 0 ? 0 : (v > TB - 2 ? TB - 2 : v);
        *idx = v; *f = tt - (float)v;
    };

    int bidx[4];
    float ff[4][3];
#pragma unroll
    for (int p = 0; p < 4; ++p) {
        float t0 = (y[p][0] + 1.0f) * TB_SCALE;
        float t1 = (y[p][1] + 1.0f) * TB_SCALE;
        float t2 = (y[p][2] + 1.0f) * TB_SCALE;
        int i0, i1, i2;
        cell(t0, &i0, &ff[p][0]);
        cell(t1, &i1, &ff[p][1]);
        cell(t2, &i2, &ff[p][2]);
        bidx[p] = (i0 * TB + i1) * TB + i2;
    }

    // Issue all 32 table gathers before any use: 32 loads in flight per wave.
    const f4* T = (const f4*)(ws + TBL_OFF);
    f4 cv[4][8];
#pragma unroll
    for (int p = 0; p < 4; ++p) {
        int b = bidx[p];
        cv[p][0] = T[b];
        cv[p][1] = T[b + 1];
        cv[p][2] = T[b + TB];
        cv[p][3] = T[b + TB + 1];
        cv[p][4] = T[b + TB2];
        cv[p][5] = T[b + TB2 + 1];
        cv[p][6] = T[b + TB2 + TB];
        cv[p][7] = T[b + TB2 + TB + 1];
    }

    float c1v[4][3];
#pragma unroll
    for (int p = 0; p < 4; ++p) {
        float f0 = ff[p][0], f1 = ff[p][1], f2 = ff[p][2];
        {
            float a00 = lerp1(cv[p][0].x, cv[p][1].x, f2), a01 = lerp1(cv[p][2].x, cv[p][3].x, f2);
            float a10 = lerp1(cv[p][4].x, cv[p][5].x, f2), a11 = lerp1(cv[p][6].x, cv[p][7].x, f2);
            c1v[p][0] = lerp1(lerp1(a00, a01, f1), lerp1(a10, a11, f1), f0);
        }
        {
            float a00 = lerp1(cv[p][0].y, cv[p][1].y, f2), a01 = lerp1(cv[p][2].y, cv[p][3].y, f2);
            float a10 = lerp1(cv[p][4].y, cv[p][5].y, f2), a11 = lerp1(cv[p][6].y, cv[p][7].y, f2);
            c1v[p][1] = lerp1(lerp1(a00, a01, f1), lerp1(a10, a11, f1), f0);
        }
        {
            float a00 = lerp1(cv[p][0].z, cv[p][1].z, f2), a01 = lerp1(cv[p][2].z, cv[p][3].z, f2);
            float a10 = lerp1(cv[p][4].z, cv[p][5].z, f2), a11 = lerp1(cv[p][6].z, cv[p][7].z, f2);
            c1v[p][2] = lerp1(lerp1(a00, a01, f1), lerp1(a10, a11, f1), f0);
        }
    }

    // c1 out: 12 contiguous floats, 16B-aligned -> 3x nontemporal dwordx4.
    {
        float* dst = out + NPTS + 12 * t;
        f4 s0 = {c1v[0][0], c1v[0][1], c1v[0][2], c1v[1][0]};
        f4 s1 = {c1v[1][1], c1v[1][2], c1v[2][0], c1v[2][1]};
        f4 s2 = {c1v[2][2], c1v[3][0], c1v[3][1], c1v[3][2]};
        __builtin_nontemporal_store(s0, (f4*)dst);
        __builtin_nontemporal_store(s1, (f4*)dst + 1);
        __builtin_nontemporal_store(s2, (f4*)dst + 2);
    }

    const unsigned char* V8 = (const unsigned char*)ws + VOL8_OFF_B;
    f4 o;
#pragma unroll
    for (int p = 0; p < 4; ++p) {
        float sraw = sample3d_u8(V8, c1v[p][0], c1v[p][1], c1v[p][2]);
        o[p] = __builtin_fmaf(sraw, 2.0f / 255.0f, -1.0f);  // 2*(s/255) - 1
    }
    __builtin_nontemporal_store(o, (f4*)(out + 4 * t));
}

// Fallback direct kernel (R12 champion, 2 pts/thread) for small ws_size.
__global__ __launch_bounds__(64) void diffeo_kernel(
    const void* __restrict__ coords,
    const float* __restrict__ ws,
    const void* __restrict__ vol,
    float* __restrict__ out) {
    int t = blockIdx.x * 64 + threadIdx.x;   // pair index
    if (t >= NPTS / 2) return;

    const int* flags = (const int*)(ws + 1024);
    int cbf = flags[0];
    int vbf = flags[1];

    v2f y0, y1, y2;
    if (cbf) {
        const __hip_bfloat16* C = (const __hip_bfloat16*)coords;
        int b = 6 * t;
        y0.x = bf2f(C[b + 0]); y1.x = bf2f(C[b + 1]); y2.x = bf2f(C[b + 2]);
        y0.y = bf2f(C[b + 3]); y1.y = bf2f(C[b + 4]); y2.y = bf2f(C[b + 5]);
    } else {
        const float* C = (const float*)coords;
        int b = 6 * t;
        y0.x = C[b + 0]; y1.x = C[b + 1]; y2.x = C[b + 2];
        y0.y = C[b + 3]; y1.y = C[b + 4]; y2.y = C[b + 5];
    }

    integrate2(ws, y0, y1, y2);

    int b = 6 * t;
    out[NPTS + b + 0] = y0.x; out[NPTS + b + 1] = y1.x; out[NPTS + b + 2] = y2.x;
    out[NPTS + b + 3] = y0.y; out[NPTS + b + 4] = y1.y; out[NPTS + b + 5] = y2.y;

    float sA = sample3d(vol, vbf, y0.x, y1.x, y2.x);
    float sB = sample3d(vol, vbf, y0.y, y1.y, y2.y);
    out[2 * t + 0] = __builtin_fmaf(2.0f, sA, -1.0f);
    out[2 * t + 1] = __builtin_fmaf(2.0f, sB, -1.0f);
}

extern "C" void kernel_launch(void* const* d_in, const int* in_sizes, int n_in,
                              void* d_out, int out_size, void* d_ws, size_t ws_size,
                              hipStream_t stream) {
    const void* coords = d_in[0];
    const void* W1_0 = d_in[1];
    const void* b1_0 = d_in[2];
    const void* W2_0 = d_in[3];
    const void* b2_0 = d_in[4];
    const void* W1_1 = d_in[5];
    const void* b1_1 = d_in[6];
    const void* W2_1 = d_in[7];
    const void* b2_1 = d_in[8];
    const void* vol  = d_in[9];
    float* out = (float*)d_out;
    float* ws = (float*)d_ws;

    setup_kernel<<<1, 1024, 0, stream>>>(coords, W1_0, b1_0, W2_0, b2_0,
                                         W1_1, b1_1, W2_1, b2_1, vol, ws);
    if (ws_size >= WS_NEED) {
        unsigned char* vol8 = (unsigned char*)ws + VOL8_OFF_B;
        conv_vol_kernel<<<VOL_N / 256, 256, 0, stream>>>(vol, ws, vol8);
        int node_quads = (TB3 + 3) / 4;                  // 29413
        build_kernel<<<(node_quads + 63) / 64, 64, 0, stream>>>(ws, ws + TBL_OFF);
        query_kernel<<<NPTS / 1024, 256, 0, stream>>>(coords, ws, out);
    } else {
        diffeo_kernel<<<(NPTS / 2) / 64, 64, 0, stream>>>(coords, ws, vol, out);
    }
}

// Round 3
// 166.494 us; speedup vs baseline: 1.0438x; 1.0438x over previous
//
#include <hip/hip_runtime.h>
#include <hip/hip_bf16.h>

#define NPTS (96 * 96 * 96)   // 884736 points, divisible by 1024
#define HID 64
#define H_EFF 0.2f            // RK4 1 step/ODE — verified error << bf16 floor (R7/R8)

// Lookup table of the composed diffeomorphism on [-1,1]^3, stored as
// int16-quantized PAIR entries: entry(i0,i1,i2) = {node(i2), node(i2+1)},
// 8 shorts = 16 B aligned. One dwordx4 fetches BOTH x-taps -> the 8 trilerp
// taps cost 4 scattered requests instead of 8. Quant scale 8192 covers
// |c1| < 4 with abs err <= 6.1e-5 (budget ~2.3e-4, R10).
#define TB  49
#define TB2 (TB * TB)         // 2401
#define TB3 (TB * TB * TB)    // 117649 (odd)
#define TB_SCALE 24.0f        // (y+1)*24 -> node index; spacing 1/24
#define TB_INV   0.0416666679f
#define QS   8192.0f          // int16 quant scale
#define QSI  (1.0f / 8192.0f)
#define TBL_OFF_B 4128        // byte offset of pair-table in ws (16B aligned)
#define VOL_N   (128 * 128 * 128)
// Paired u8 volume: VP[z][y][x] = V[x] | V[x+1]<<8 (ushort), 4.19 MB.
// 8 vol taps -> 4 ushort requests. Total gather set 1.88+4.19 = 6.1 MB.
#define VOLP_OFF_B ((size_t)TBL_OFF_B + (size_t)TB3 * 16)
#define WS_NEED (VOLP_OFF_B + (size_t)VOL_N * 2)

typedef float v2f __attribute__((ext_vector_type(2)));
typedef float f4  __attribute__((ext_vector_type(4)));
typedef unsigned u2 __attribute__((ext_vector_type(2)));
typedef short s4v __attribute__((ext_vector_type(4)));
typedef short s8v __attribute__((ext_vector_type(8)));

__device__ __forceinline__ float bf2f(const __hip_bfloat16 v) {
    return __bfloat162float(v);
}
__device__ __forceinline__ v2f splat(float x) { v2f r; r.x = x; r.y = x; return r; }
__device__ __forceinline__ v2f vfma(v2f a, v2f b, v2f c) {
    return __builtin_elementwise_fma(a, b, c);
}
__device__ __forceinline__ float lerp1(float a, float b, float f) {
    return __builtin_fmaf(f, b - a, a);
}

// ---------------------------------------------------------------------------
// Setup: dtype detection + weight fold into ws[0..1024), flags at ws[1024..1026).
// W1' = K*W1, b1' = K*b1 (K=2*log2 e), W2' = -2*W2, b2'' = b2 + sum_j W2[j][k]
//   =>  out = b2'' + sum_j W2'_jk * rcp(1 + 2^pre')
// ---------------------------------------------------------------------------
__global__ void setup_kernel(
    const void* __restrict__ coords,
    const void* __restrict__ W1_0, const void* __restrict__ b1_0,
    const void* __restrict__ W2_0, const void* __restrict__ b2_0,
    const void* __restrict__ W1_1, const void* __restrict__ b1_1,
    const void* __restrict__ W2_1, const void* __restrict__ b2_1,
    const void* __restrict__ vol,
    float* __restrict__ ws) {
    __shared__ int sflags[3];
    int tid = threadIdx.x;
    if (tid < 64) {
        auto sane = [](const void* p, int i) -> bool {
            unsigned e = (((const unsigned short*)p)[i] >> 7) & 0xFFu;
            return e >= 97u && e <= 129u;
        };
        unsigned long long m;
        m = __ballot(sane(W1_0, tid));
        if (tid == 0) sflags[2] = (__popcll(m) >= 52) ? 1 : 0;
        m = __ballot(sane(coords, tid));
        if (tid == 0) sflags[0] = (__popcll(m) >= 52) ? 1 : 0;
        m = __ballot(sane(vol, tid));
        if (tid == 0) sflags[1] = (__popcll(m) >= 52) ? 1 : 0;
    }
    __syncthreads();
    int isbf = sflags[2];
    const float K = 2.88539008177792681472f;  // 2/ln(2)
    int ode = tid >> 9;
    int r = tid & 511;
    const void* W1 = ode ? W1_1 : W1_0;
    const void* b1 = ode ? b1_1 : b1_0;
    const void* W2 = ode ? W2_1 : W2_0;
    const void* b2 = ode ? b2_1 : b2_0;
    auto ld = [&](const void* p, int idx) -> float {
        return isbf ? bf2f(((const __hip_bfloat16*)p)[idx]) : ((const float*)p)[idx];
    };
    float v = 0.0f;
    if (r < 192)       v = K * ld(W1, r);
    else if (r < 256)  v = K * ld(b1, r - 192);
    else if (r < 448)  v = -2.0f * ld(W2, r - 256);
    else if (r < 451) {
        int k = r - 448;
        float s = ld(b2, k);
        for (int j = 0; j < HID; ++j) s += ld(W2, 3 * j + k);
        v = s;
    }
    ws[(ode << 9) + r] = v;
    if (tid < 2) ((int*)(ws + 1024))[tid] = sflags[tid];
}

// Quantize vol (bf16 or fp32) to u8 PAIRS: VP[i] = q(V[i]) | q(V[i+1])<<8.
// Hi byte at row end x=127 is next-row garbage — never used (x1=128 invalid
// -> tap zeroed). Recon err <= 1/510 -> out0 contribution <= 3.9e-3.
__global__ __launch_bounds__(256) void conv_vol_kernel(
    const void* __restrict__ vol,
    const float* __restrict__ ws,
    unsigned short* __restrict__ volp) {
    int i = blockIdx.x * 256 + threadIdx.x;
    if (i >= VOL_N) return;
    int vbf = ((const int*)(ws + 1024))[1];
    int j = i + 1 < VOL_N ? i + 1 : VOL_N - 1;
    float va, vb;
    if (vbf) {
        va = bf2f(((const __hip_bfloat16*)vol)[i]);
        vb = bf2f(((const __hip_bfloat16*)vol)[j]);
    } else {
        va = ((const float*)vol)[i];
        vb = ((const float*)vol)[j];
    }
    float qa = __builtin_fmaf(va, 255.0f, 0.5f);
    float qb = __builtin_fmaf(vb, 255.0f, 0.5f);
    qa = qa < 0.f ? 0.f : (qa > 255.f ? 255.f : qa);
    qb = qb < 0.f ? 0.f : (qb > 255.f ? 255.f : qb);
    volp[i] = (unsigned short)((unsigned)qa | ((unsigned)qb << 8));
}

// MLP eval for a PAIR of points. Shared-rcp: one v_rcp of qx*qy recovers both
// reciprocals. q in [1, ~3000]; v_rcp rel err ~1e-7 (accuracy budget R10:
// c1 err must be <= ~2.3e-4; one-Newton bit-rcp at 3.6e-3 FAILED).
__device__ __forceinline__ void mlp_f2(const float* __restrict__ w,
                                       v2f y0, v2f y1, v2f y2,
                                       v2f& o0, v2f& o1, v2f& o2) {
    v2f a0 = splat(w[448]), a1 = splat(w[449]), a2 = splat(w[450]);
#pragma unroll 8
    for (int j = 0; j < HID; ++j) {
        v2f pre = vfma(y0, splat(w[j]),
                  vfma(y1, splat(w[64 + j]),
                  vfma(y2, splat(w[128 + j]), splat(w[192 + j]))));
        v2f e;
        e.x = __builtin_amdgcn_exp2f(pre.x);
        e.y = __builtin_amdgcn_exp2f(pre.y);
        v2f q = e + splat(1.0f);
        float rP = __builtin_amdgcn_rcpf(q.x * q.y);
        v2f r;
        r.x = q.y * rP;
        r.y = q.x * rP;
        a0 = vfma(r, splat(w[256 + 3 * j + 0]), a0);
        a1 = vfma(r, splat(w[256 + 3 * j + 1]), a1);
        a2 = vfma(r, splat(w[256 + 3 * j + 2]), a2);
    }
    o0 = a0; o1 = a1; o2 = a2;
}

// Full 2-ODE RK4 (1 step of h=0.2 each) for a pair of points, in-place.
__device__ __forceinline__ void integrate2(const float* __restrict__ ws,
                                           v2f& y0, v2f& y1, v2f& y2) {
    const float h = H_EFF;
#pragma unroll 1
    for (int ode = 0; ode < 2; ++ode) {
        const float* __restrict__ w = ws + (ode << 9);
        v2f k0 = splat(0.f), k1 = splat(0.f), k2 = splat(0.f);
        v2f s0 = splat(0.f), s1 = splat(0.f), s2 = splat(0.f);
#pragma unroll 1
        for (int e = 0; e < 4; ++e) {
            float ae = (e == 0) ? 0.0f : ((e == 3) ? h : 0.5f * h);
            float we = (e == 1 || e == 2) ? 2.0f : 1.0f;
            v2f aev = splat(ae), wev = splat(we);
            v2f f0, f1, f2;
            mlp_f2(w,
                   vfma(aev, k0, y0),
                   vfma(aev, k1, y1),
                   vfma(aev, k2, y2),
                   f0, f1, f2);
            k0 = f0; k1 = f1; k2 = f2;
            s0 = vfma(wev, k0, s0);
            s1 = vfma(wev, k1, s1);
            s2 = vfma(wev, k2, s2);
        }
        v2f h6 = splat(h / 6.0f);
        y0 = vfma(h6, s0, y0);
        y1 = vfma(h6, s1, y1);
        y2 = vfma(h6, s2, y2);
    }
}

// ---------------------------------------------------------------------------
// Table build: integrate the 49^3 lattice nodes (2 per thread, 256-thread
// blocks -> 920 waves fill ~90% of SIMDs; R2's 64-thread variant left half
// the SIMDs idle). Each node n stores int16-quantized c1 into entry[n].lo
// and entry[n-1].hi (pair layout).
// ---------------------------------------------------------------------------
__global__ __launch_bounds__(256) void build_kernel(const float* __restrict__ ws,
                                                    short* __restrict__ tbl) {
    int t = blockIdx.x * 256 + threadIdx.x;   // node-pair index
    int nA = 2 * t;
    if (nA >= TB3) return;
    int nB = nA + 1;
    int nBc = nB < TB3 ? nB : (TB3 - 1);

    auto node_y = [](int n, float* a, float* b, float* c) {
        int i0 = n / TB2;
        int rem = n - i0 * TB2;
        int i1 = rem / TB;
        int i2 = rem - i1 * TB;
        *a = __builtin_fmaf((float)i0, TB_INV, -1.0f);
        *b = __builtin_fmaf((float)i1, TB_INV, -1.0f);
        *c = __builtin_fmaf((float)i2, TB_INV, -1.0f);
    };
    float ax, bx, cxv, ay, by, cyv;
    node_y(nA,  &ax, &bx, &cxv);
    node_y(nBc, &ay, &by, &cyv);
    v2f y0, y1, y2;
    y0.x = ax;  y1.x = bx;  y2.x = cxv;
    y0.y = ay;  y1.y = by;  y2.y = cyv;

    integrate2(ws, y0, y1, y2);

    auto quant = [](float v) -> short {
        float q = v * QS;
        q = q < -32767.f ? -32767.f : (q > 32767.f ? 32767.f : q);
        return (short)(int)rintf(q);
    };
    s4v qA = { quant(y0.x), quant(y1.x), quant(y2.x), 0 };
    s4v qB = { quant(y0.y), quant(y1.y), quant(y2.y), 0 };

    s4v* T = (s4v*)tbl;   // 2 s4v per 16B entry: [2n]=lo(entry n), [2n+1]=hi
    T[2 * nA] = qA;                      // entry nA .lo
    if (nA > 0) T[2 * nA - 1] = qA;      // entry nA-1 .hi
    if (nB < TB3) {
        T[2 * nB] = qB;                  // entry nB .lo
        T[2 * nB - 1] = qB;              // entry nA .hi
    }
}

// fp-source grid-sample for the fallback path.
__device__ __forceinline__ float sample3d(const void* __restrict__ vol, int vbf,
                                          float cz, float cy, float cx) {
    float fx = (cx + 1.0f) * 64.0f - 0.5f;
    float fy = (cy + 1.0f) * 64.0f - 0.5f;
    float fz = (cz + 1.0f) * 64.0f - 0.5f;
    float x0f = floorf(fx), y0f = floorf(fy), z0f = floorf(fz);
    float tx = fx - x0f, ty = fy - y0f, tz = fz - z0f;
    int x0 = (int)x0f, y0 = (int)y0f, z0 = (int)z0f;
    int x1 = x0 + 1, y1 = y0 + 1, z1 = z0 + 1;
    auto clampi = [](int v) { return v < 0 ? 0 : (v > 127 ? 127 : v); };
    auto valid = [](int zi, int yi, int xi) -> bool {
        return ((unsigned)zi < 128u) && ((unsigned)yi < 128u) && ((unsigned)xi < 128u);
    };
    int xc0 = clampi(x0), xc1 = clampi(x1);
    int yc0 = clampi(y0), yc1 = clampi(y1);
    int zc0 = clampi(z0), zc1 = clampi(z1);
    int idx[8] = {
        (zc0 << 14) | (yc0 << 7) | xc0, (zc0 << 14) | (yc0 << 7) | xc1,
        (zc0 << 14) | (yc1 << 7) | xc0, (zc0 << 14) | (yc1 << 7) | xc1,
        (zc1 << 14) | (yc0 << 7) | xc0, (zc1 << 14) | (yc0 << 7) | xc1,
        (zc1 << 14) | (yc1 << 7) | xc0, (zc1 << 14) | (yc1 << 7) | xc1 };
    float v[8];
    if (vbf) {
        const __hip_bfloat16* V = (const __hip_bfloat16*)vol;
#pragma unroll
        for (int q = 0; q < 8; ++q) v[q] = bf2f(V[idx[q]]);
    } else {
        const float* V = (const float*)vol;
#pragma unroll
        for (int q = 0; q < 8; ++q) v[q] = V[idx[q]];
    }
    if (!valid(z0, y0, x0)) v[0] = 0.f;
    if (!valid(z0, y0, x1)) v[1] = 0.f;
    if (!valid(z0, y1, x0)) v[2] = 0.f;
    if (!valid(z0, y1, x1)) v[3] = 0.f;
    if (!valid(z1, y0, x0)) v[4] = 0.f;
    if (!valid(z1, y0, x1)) v[5] = 0.f;
    if (!valid(z1, y1, x0)) v[6] = 0.f;
    if (!valid(z1, y1, x1)) v[7] = 0.f;
    return v[0] * (1.f - tz) * (1.f - ty) * (1.f - tx) +
           v[1] * (1.f - tz) * (1.f - ty) * tx +
           v[2] * (1.f - tz) * ty * (1.f - tx) +
           v[3] * (1.f - tz) * ty * tx +
           v[4] * tz * (1.f - ty) * (1.f - tx) +
           v[5] * tz * (1.f - ty) * tx +
           v[6] * tz * ty * (1.f - tx) +
           v[7] * tz * ty * tx;
}

// ---------------------------------------------------------------------------
// Query: 4 pts/thread. Per point: 4 dwordx4 pair-table gathers + 4 ushort
// pair-vol gathers = 8 scattered requests (was 16). Request-rate model:
// 0.5 req/cy/CU observed -> expect ~27 us.
// ---------------------------------------------------------------------------
__global__ __launch_bounds__(256) void query_kernel(
    const void* __restrict__ coords,
    const float* __restrict__ ws,
    float* __restrict__ out) {
    int t = blockIdx.x * 256 + threadIdx.x;   // quad-of-points index
    if (t >= NPTS / 4) return;

    const int* flags = (const int*)(ws + 1024);
    int cbf = flags[0];

    float y[4][3];
    if (cbf) {
        const u2* C2 = (const u2*)((const unsigned short*)coords + 12 * t);
        u2 ua = __builtin_nontemporal_load(C2);
        u2 ub = __builtin_nontemporal_load(C2 + 1);
        u2 uc = __builtin_nontemporal_load(C2 + 2);
        unsigned uu[6] = {ua.x, ua.y, ub.x, ub.y, uc.x, uc.y};
#pragma unroll
        for (int p = 0; p < 4; ++p)
#pragma unroll
            for (int d = 0; d < 3; ++d) {
                int k = 3 * p + d;
                unsigned h = uu[k >> 1];
                h = (k & 1) ? (h & 0xFFFF0000u) : (h << 16);
                y[p][d] = __builtin_bit_cast(float, h);
            }
    } else {
        const f4* C4 = (const f4*)((const float*)coords + 12 * t);
        f4 a = __builtin_nontemporal_load(C4);
        f4 b = __builtin_nontemporal_load(C4 + 1);
        f4 c = __builtin_nontemporal_load(C4 + 2);
        y[0][0] = a.x; y[0][1] = a.y; y[0][2] = a.z;
        y[1][0] = a.w; y[1][1] = b.x; y[1][2] = b.y;
        y[2][0] = b.z; y[2][1] = b.w; y[2][2] = c.x;
        y[3][0] = c.y; y[3][1] = c.z; y[3][2] = c.w;
    }

    auto cell = [](float tt, int* idx, float* f) {
        int v = (int)floorf(tt);
        v = v < 0 ? 0 : (v > TB - 2 ? TB - 2 : v);
        *idx = v; *f = tt - (float)v;
    };

    int bidx[4];
    float ff[4][3];
#pragma unroll
    for (int p = 0; p < 4; ++p) {
        float t0 = (y[p][0] + 1.0f) * TB_SCALE;
        float t1 = (y[p][1] + 1.0f) * TB_SCALE;
        float t2 = (y[p][2] + 1.0f) * TB_SCALE;
        int i0, i1, i2;
        cell(t0, &i0, &ff[p][0]);
        cell(t1, &i1, &ff[p][1]);
        cell(t2, &i2, &ff[p][2]);
        bidx[p] = (i0 * TB + i1) * TB + i2;
    }

    // Pair-table gathers: each entry = {node(i2), node(i2+1)} as 8 shorts.
    const s8v* E = (const s8v*)((const char*)ws + TBL_OFF_B);
    s8v ev[4][4];
#pragma unroll
    for (int p = 0; p < 4; ++p) {
        int b = bidx[p];
        ev[p][0] = E[b];                 // (i0  ,i1  ) -> c000|c001
        ev[p][1] = E[b + TB];            // (i0  ,i1+1) -> c010|c011
        ev[p][2] = E[b + TB2];           // (i0+1,i1  ) -> c100|c101
        ev[p][3] = E[b + TB2 + TB];      // (i0+1,i1+1) -> c110|c111
    }

    float c1v[4][3];
#pragma unroll
    for (int p = 0; p < 4; ++p) {
        float f0 = ff[p][0], f1 = ff[p][1], f2 = ff[p][2];
#pragma unroll
        for (int d = 0; d < 3; ++d) {
            // lerp along i2 inside each entry (lo=idx d, hi=idx 4+d)
            float a00 = lerp1((float)ev[p][0][d], (float)ev[p][0][4 + d], f2);
            float a01 = lerp1((float)ev[p][1][d], (float)ev[p][1][4 + d], f2);
            float a10 = lerp1((float)ev[p][2][d], (float)ev[p][2][4 + d], f2);
            float a11 = lerp1((float)ev[p][3][d], (float)ev[p][3][4 + d], f2);
            // scale folded once at the end (lerp is linear in the values)
            c1v[p][d] = lerp1(lerp1(a00, a01, f1), lerp1(a10, a11, f1), f0) * QSI;
        }
    }

    // c1 out: 12 contiguous floats, 16B-aligned -> 3x dwordx4 (plain stores;
    // R2 showed nontemporal STORES inflate WRITE_SIZE 13.8->21.6 MB).
    {
        float* dst = out + NPTS + 12 * t;
        f4 s0 = {c1v[0][0], c1v[0][1], c1v[0][2], c1v[1][0]};
        f4 s1 = {c1v[1][1], c1v[1][2], c1v[2][0], c1v[2][1]};
        f4 s2 = {c1v[2][2], c1v[3][0], c1v[3][1], c1v[3][2]};
        ((f4*)dst)[0] = s0;
        ((f4*)dst)[1] = s1;
        ((f4*)dst)[2] = s2;
    }

    // Pair-vol sample: 4 ushort gathers per point.
    const unsigned short* VP =
        (const unsigned short*)((const char*)ws + VOLP_OFF_B);
    f4 o;
#pragma unroll
    for (int p = 0; p < 4; ++p) {
        float cx = c1v[p][0], cy = c1v[p][1], cz = c1v[p][2];
        float fx = (cz + 1.0f) * 64.0f - 0.5f;   // NOTE: reference maps
        float fy = (cy + 1.0f) * 64.0f - 0.5f;   // c[...,2]->x, c[...,1]->y,
        float fz = (cx + 1.0f) * 64.0f - 0.5f;   // c[...,0]->z (as before:
        // previous code called sample(V8, c1x, c1y, c1z) with cz=c1x first).
        float x0f = floorf(fx), y0f = floorf(fy), z0f = floorf(fz);
        float tx = fx - x0f, ty = fy - y0f, tz = fz - z0f;
        int x0 = (int)x0f, y0 = (int)y0f, z0 = (int)z0f;
        int x1 = x0 + 1, y1 = y0 + 1, z1 = z0 + 1;
        auto clampi = [](int v, int hi) { return v < 0 ? 0 : (v > hi ? hi : v); };
        int xa  = clampi(x0, 126);
        int yc0 = clampi(y0, 127), yc1 = clampi(y1, 127);
        int zc0 = clampi(z0, 127), zc1 = clampi(z1, 127);
        bool xlo = (x0 == xa);   // else x0 clamped: lo/hi swap
        unsigned short w00 = VP[(zc0 << 14) | (yc0 << 7) | xa];
        unsigned short w01 = VP[(zc0 << 14) | (yc1 << 7) | xa];
        unsigned short w10 = VP[(zc1 << 14) | (yc0 << 7) | xa];
        unsigned short w11 = VP[(zc1 << 14) | (yc1 << 7) | xa];
        auto ext = [&](unsigned short w, bool lo) -> float {
            return (float)(lo ? (w & 0xFF) : (w >> 8));
        };
        float v0 = ext(w00, xlo),  v1 = ext(w00, !xlo);   // (z0,y0,x0),(z0,y0,x1)
        float v2 = ext(w01, xlo),  v3 = ext(w01, !xlo);   // (z0,y1,..)
        float v4 = ext(w10, xlo),  v5 = ext(w10, !xlo);   // (z1,y0,..)
        float v6 = ext(w11, xlo),  v7 = ext(w11, !xlo);   // (z1,y1,..)
        auto valid = [](int zi, int yi, int xi) -> bool {
            return ((unsigned)zi < 128u) && ((unsigned)yi < 128u) &&
                   ((unsigned)xi < 128u);
        };
        if (!valid(z0, y0, x0)) v0 = 0.f;
        if (!valid(z0, y0, x1)) v1 = 0.f;
        if (!valid(z0, y1, x0)) v2 = 0.f;
        if (!valid(z0, y1, x1)) v3 = 0.f;
        if (!valid(z1, y0, x0)) v4 = 0.f;
        if (!valid(z1, y0, x1)) v5 = 0.f;
        if (!valid(z1, y1, x0)) v6 = 0.f;
        if (!valid(z1, y1, x1)) v7 = 0.f;
        float sraw =
            v0 * (1.f - tz) * (1.f - ty) * (1.f - tx) +
            v1 * (1.f - tz) * (1.f - ty) * tx +
            v2 * (1.f - tz) * ty * (1.f - tx) +
            v3 * (1.f - tz) * ty * tx +
            v4 * tz * (1.f - ty) * (1.f - tx) +
            v5 * tz * (1.f - ty) * tx +
            v6 * tz * ty * (1.f - tx) +
            v7 * tz * ty * tx;
        o[p] = __builtin_fmaf(sraw, 2.0f / 255.0f, -1.0f);  // 2*(s/255) - 1
    }
    ((f4*)(out + 4 * t))[0] = o;
}

// Fallback direct kernel (R12 champion, 2 pts/thread) for small ws_size.
__global__ __launch_bounds__(64) void diffeo_kernel(
    const void* __restrict__ coords,
    const float* __restrict__ ws,
    const void* __restrict__ vol,
    float* __restrict__ out) {
    int t = blockIdx.x * 64 + threadIdx.x;   // pair index
    if (t >= NPTS / 2) return;

    const int* flags = (const int*)(ws + 1024);
    int cbf = flags[0];
    int vbf = flags[1];

    v2f y0, y1, y2;
    if (cbf) {
        const __hip_bfloat16* C = (const __hip_bfloat16*)coords;
        int b = 6 * t;
        y0.x = bf2f(C[b + 0]); y1.x = bf2f(C[b + 1]); y2.x = bf2f(C[b + 2]);
        y0.y = bf2f(C[b + 3]); y1.y = bf2f(C[b + 4]); y2.y = bf2f(C[b + 5]);
    } else {
        const float* C = (const float*)coords;
        int b = 6 * t;
        y0.x = C[b + 0]; y1.x = C[b + 1]; y2.x = C[b + 2];
        y0.y = C[b + 3]; y1.y = C[b + 4]; y2.y = C[b + 5];
    }

    integrate2(ws, y0, y1, y2);

    int b = 6 * t;
    out[NPTS + b + 0] = y0.x; out[NPTS + b + 1] = y1.x; out[NPTS + b + 2] = y2.x;
    out[NPTS + b + 3] = y0.y; out[NPTS + b + 4] = y1.y; out[NPTS + b + 5] = y2.y;

    float sA = sample3d(vol, vbf, y0.x, y1.x, y2.x);
    float sB = sample3d(vol, vbf, y0.y, y1.y, y2.y);
    out[2 * t + 0] = __builtin_fmaf(2.0f, sA, -1.0f);
    out[2 * t + 1] = __builtin_fmaf(2.0f, sB, -1.0f);
}

extern "C" void kernel_launch(void* const* d_in, const int* in_sizes, int n_in,
                              void* d_out, int out_size, void* d_ws, size_t ws_size,
                              hipStream_t stream) {
    const void* coords = d_in[0];
    const void* W1_0 = d_in[1];
    const void* b1_0 = d_in[2];
    const void* W2_0 = d_in[3];
    const void* b2_0 = d_in[4];
    const void* W1_1 = d_in[5];
    const void* b1_1 = d_in[6];
    const void* W2_1 = d_in[7];
    const void* b2_1 = d_in[8];
    const void* vol  = d_in[9];
    float* out = (float*)d_out;
    float* ws = (float*)d_ws;

    setup_kernel<<<1, 1024, 0, stream>>>(coords, W1_0, b1_0, W2_0, b2_0,
                                         W1_1, b1_1, W2_1, b2_1, vol, ws);
    if (ws_size >= WS_NEED) {
        unsigned short* volp = (unsigned short*)((char*)ws + VOLP_OFF_B);
        short* tbl = (short*)((char*)ws + TBL_OFF_B);
        conv_vol_kernel<<<VOL_N / 256, 256, 0, stream>>>(vol, ws, volp);
        int node_pairs = (TB3 + 1) / 2;                  // 58825
        build_kernel<<<(node_pairs + 255) / 256, 256, 0, stream>>>(ws, tbl);
        query_kernel<<<NPTS / 1024, 256, 0, stream>>>(coords, ws, out);
    } else {
        diffeo_kernel<<<(NPTS / 2) / 64, 64, 0, stream>>>(coords, ws, vol, out);
    }
}

// Round 4
// 160.100 us; speedup vs baseline: 1.0855x; 1.0399x over previous
//
#include <hip/hip_runtime.h>
#include <hip/hip_bf16.h>

#define NPTS (96 * 96 * 96)   // 884736 points, divisible by 1024
#define HID 64
#define H_EFF 0.2f            // RK4 1 step/ODE — verified error << bf16 floor (R7/R8)

// Lookup table of the composed diffeomorphism on [-1,1]^3, stored as
// int16-quantized PAIR entries: entry(i0,i1,i2) = {node(i2), node(i2+1)},
// 8 shorts = 16 B aligned. One dwordx4 fetches BOTH x-taps -> the 8 trilerp
// taps cost 4 scattered requests. Quant scale 8192: err 6.1e-5 -> +2.6e-3
// absmax via vol gradient (R3: 0.0195, passed). Budget nearly spent.
// WORKING SET RULE (R3 lesson): table + vol MUST stay < 4 MiB/XCD L2.
// Pair-table 1.88 MB + u8 vol 2.10 MB = 3.98 MB fits; R3's paired vol
// (4.19 MB, total 6.1 MB) thrashed L2: FETCH 20->83 MB, query 46->51 us.
#define TB  49
#define TB2 (TB * TB)         // 2401
#define TB3 (TB * TB * TB)    // 117649 (odd)
#define TB_SCALE 24.0f        // (y+1)*24 -> node index; spacing 1/24
#define TB_INV   0.0416666679f
#define QS   8192.0f          // int16 quant scale
#define QSI  (1.0f / 8192.0f)
#define TBL_OFF_B 4128        // byte offset of pair-table in ws (16B aligned)
#define VOL_N   (128 * 128 * 128)
#define VOL8_OFF_B ((size_t)TBL_OFF_B + (size_t)TB3 * 16)   // u8 vol offset
#define WS_NEED (VOL8_OFF_B + (size_t)VOL_N)

typedef float v2f __attribute__((ext_vector_type(2)));
typedef float f4  __attribute__((ext_vector_type(4)));
typedef unsigned u2 __attribute__((ext_vector_type(2)));
typedef short s4v __attribute__((ext_vector_type(4)));
typedef short s8v __attribute__((ext_vector_type(8)));

__device__ __forceinline__ float bf2f(const __hip_bfloat16 v) {
    return __bfloat162float(v);
}
__device__ __forceinline__ v2f splat(float x) { v2f r; r.x = x; r.y = x; return r; }
__device__ __forceinline__ v2f vfma(v2f a, v2f b, v2f c) {
    return __builtin_elementwise_fma(a, b, c);
}
__device__ __forceinline__ float lerp1(float a, float b, float f) {
    return __builtin_fmaf(f, b - a, a);
}

// ---------------------------------------------------------------------------
// Setup: dtype detection + weight fold into ws[0..1024), flags at ws[1024..1026).
// W1' = K*W1, b1' = K*b1 (K=2*log2 e), W2' = -2*W2, b2'' = b2 + sum_j W2[j][k]
//   =>  out = b2'' + sum_j W2'_jk * rcp(1 + 2^pre')
// ---------------------------------------------------------------------------
__global__ void setup_kernel(
    const void* __restrict__ coords,
    const void* __restrict__ W1_0, const void* __restrict__ b1_0,
    const void* __restrict__ W2_0, const void* __restrict__ b2_0,
    const void* __restrict__ W1_1, const void* __restrict__ b1_1,
    const void* __restrict__ W2_1, const void* __restrict__ b2_1,
    const void* __restrict__ vol,
    float* __restrict__ ws) {
    __shared__ int sflags[3];
    int tid = threadIdx.x;
    if (tid < 64) {
        auto sane = [](const void* p, int i) -> bool {
            unsigned e = (((const unsigned short*)p)[i] >> 7) & 0xFFu;
            return e >= 97u && e <= 129u;
        };
        unsigned long long m;
        m = __ballot(sane(W1_0, tid));
        if (tid == 0) sflags[2] = (__popcll(m) >= 52) ? 1 : 0;
        m = __ballot(sane(coords, tid));
        if (tid == 0) sflags[0] = (__popcll(m) >= 52) ? 1 : 0;
        m = __ballot(sane(vol, tid));
        if (tid == 0) sflags[1] = (__popcll(m) >= 52) ? 1 : 0;
    }
    __syncthreads();
    int isbf = sflags[2];
    const float K = 2.88539008177792681472f;  // 2/ln(2)
    int ode = tid >> 9;
    int r = tid & 511;
    const void* W1 = ode ? W1_1 : W1_0;
    const void* b1 = ode ? b1_1 : b1_0;
    const void* W2 = ode ? W2_1 : W2_0;
    const void* b2 = ode ? b2_1 : b2_0;
    auto ld = [&](const void* p, int idx) -> float {
        return isbf ? bf2f(((const __hip_bfloat16*)p)[idx]) : ((const float*)p)[idx];
    };
    float v = 0.0f;
    if (r < 192)       v = K * ld(W1, r);
    else if (r < 256)  v = K * ld(b1, r - 192);
    else if (r < 448)  v = -2.0f * ld(W2, r - 256);
    else if (r < 451) {
        int k = r - 448;
        float s = ld(b2, k);
        for (int j = 0; j < HID; ++j) s += ld(W2, 3 * j + k);
        v = s;
    }
    ws[(ode << 9) + r] = v;
    if (tid < 2) ((int*)(ws + 1024))[tid] = sflags[tid];
}

// Quantize vol (bf16 or fp32 per flag) to uint8: q = round(v*255), v in [0,1).
// Recon err <= 1/510 -> out0 contribution <= 3.9e-3.
__global__ __launch_bounds__(256) void conv_vol_kernel(
    const void* __restrict__ vol,
    const float* __restrict__ ws,
    unsigned char* __restrict__ vol8) {
    int i = blockIdx.x * 256 + threadIdx.x;
    if (i >= VOL_N) return;
    int vbf = ((const int*)(ws + 1024))[1];
    float v = vbf ? bf2f(((const __hip_bfloat16*)vol)[i]) : ((const float*)vol)[i];
    float q = __builtin_fmaf(v, 255.0f, 0.5f);
    q = q < 0.f ? 0.f : (q > 255.f ? 255.f : q);
    vol8[i] = (unsigned char)q;
}

// MLP eval for a PAIR of points. Shared-rcp: one v_rcp of qx*qy recovers both
// reciprocals. q in [1, ~3000]; v_rcp rel err ~1e-7 (accuracy budget R10:
// c1 err must be <= ~2.3e-4; one-Newton bit-rcp at 3.6e-3 FAILED).
__device__ __forceinline__ void mlp_f2(const float* __restrict__ w,
                                       v2f y0, v2f y1, v2f y2,
                                       v2f& o0, v2f& o1, v2f& o2) {
    v2f a0 = splat(w[448]), a1 = splat(w[449]), a2 = splat(w[450]);
#pragma unroll 8
    for (int j = 0; j < HID; ++j) {
        v2f pre = vfma(y0, splat(w[j]),
                  vfma(y1, splat(w[64 + j]),
                  vfma(y2, splat(w[128 + j]), splat(w[192 + j]))));
        v2f e;
        e.x = __builtin_amdgcn_exp2f(pre.x);
        e.y = __builtin_amdgcn_exp2f(pre.y);
        v2f q = e + splat(1.0f);
        float rP = __builtin_amdgcn_rcpf(q.x * q.y);
        v2f r;
        r.x = q.y * rP;
        r.y = q.x * rP;
        a0 = vfma(r, splat(w[256 + 3 * j + 0]), a0);
        a1 = vfma(r, splat(w[256 + 3 * j + 1]), a1);
        a2 = vfma(r, splat(w[256 + 3 * j + 2]), a2);
    }
    o0 = a0; o1 = a1; o2 = a2;
}

// Full 2-ODE RK4 (1 step of h=0.2 each) for a pair of points, in-place.
__device__ __forceinline__ void integrate2(const float* __restrict__ ws,
                                           v2f& y0, v2f& y1, v2f& y2) {
    const float h = H_EFF;
#pragma unroll 1
    for (int ode = 0; ode < 2; ++ode) {
        const float* __restrict__ w = ws + (ode << 9);
        v2f k0 = splat(0.f), k1 = splat(0.f), k2 = splat(0.f);
        v2f s0 = splat(0.f), s1 = splat(0.f), s2 = splat(0.f);
#pragma unroll 1
        for (int e = 0; e < 4; ++e) {
            float ae = (e == 0) ? 0.0f : ((e == 3) ? h : 0.5f * h);
            float we = (e == 1 || e == 2) ? 2.0f : 1.0f;
            v2f aev = splat(ae), wev = splat(we);
            v2f f0, f1, f2;
            mlp_f2(w,
                   vfma(aev, k0, y0),
                   vfma(aev, k1, y1),
                   vfma(aev, k2, y2),
                   f0, f1, f2);
            k0 = f0; k1 = f1; k2 = f2;
            s0 = vfma(wev, k0, s0);
            s1 = vfma(wev, k1, s1);
            s2 = vfma(wev, k2, s2);
        }
        v2f h6 = splat(h / 6.0f);
        y0 = vfma(h6, s0, y0);
        y1 = vfma(h6, s1, y1);
        y2 = vfma(h6, s2, y2);
    }
}

// ---------------------------------------------------------------------------
// Table build: integrate the 49^3 lattice nodes (2 per thread, 256-thread
// blocks -> 920 waves). Each node n stores int16-quantized c1 into
// entry[n].lo and entry[n-1].hi (pair layout).
// ---------------------------------------------------------------------------
__global__ __launch_bounds__(256) void build_kernel(const float* __restrict__ ws,
                                                    short* __restrict__ tbl) {
    int t = blockIdx.x * 256 + threadIdx.x;   // node-pair index
    int nA = 2 * t;
    if (nA >= TB3) return;
    int nB = nA + 1;
    int nBc = nB < TB3 ? nB : (TB3 - 1);

    auto node_y = [](int n, float* a, float* b, float* c) {
        int i0 = n / TB2;
        int rem = n - i0 * TB2;
        int i1 = rem / TB;
        int i2 = rem - i1 * TB;
        *a = __builtin_fmaf((float)i0, TB_INV, -1.0f);
        *b = __builtin_fmaf((float)i1, TB_INV, -1.0f);
        *c = __builtin_fmaf((float)i2, TB_INV, -1.0f);
    };
    float ax, bx, cxv, ay, by, cyv;
    node_y(nA,  &ax, &bx, &cxv);
    node_y(nBc, &ay, &by, &cyv);
    v2f y0, y1, y2;
    y0.x = ax;  y1.x = bx;  y2.x = cxv;
    y0.y = ay;  y1.y = by;  y2.y = cyv;

    integrate2(ws, y0, y1, y2);

    auto quant = [](float v) -> short {
        float q = v * QS;
        q = q < -32767.f ? -32767.f : (q > 32767.f ? 32767.f : q);
        return (short)(int)rintf(q);
    };
    s4v qA = { quant(y0.x), quant(y1.x), quant(y2.x), 0 };
    s4v qB = { quant(y0.y), quant(y1.y), quant(y2.y), 0 };

    s4v* T = (s4v*)tbl;   // 2 s4v per 16B entry: [2n]=lo(entry n), [2n+1]=hi
    T[2 * nA] = qA;                      // entry nA .lo
    if (nA > 0) T[2 * nA - 1] = qA;      // entry nA-1 .hi
    if (nB < TB3) {
        T[2 * nB] = qB;                  // entry nB .lo
        T[2 * nB - 1] = qB;              // entry nA .hi
    }
}

// Trilinear grid-sample of the uint8 volume (128^3), align_corners=False,
// zeros padding. Returns RAW sum in [0,255] units — caller applies 2/255.
// Arg order (cz,cy,cx) matches reference reorder: fx from 3rd arg (c1[2]).
__device__ __forceinline__ float sample3d_u8(const unsigned char* __restrict__ V,
                                             float cz, float cy, float cx) {
    float fx = (cx + 1.0f) * 64.0f - 0.5f;
    float fy = (cy + 1.0f) * 64.0f - 0.5f;
    float fz = (cz + 1.0f) * 64.0f - 0.5f;
    float x0f = floorf(fx), y0f = floorf(fy), z0f = floorf(fz);
    float tx = fx - x0f, ty = fy - y0f, tz = fz - z0f;
    int x0 = (int)x0f, y0 = (int)y0f, z0 = (int)z0f;
    int x1 = x0 + 1, y1 = y0 + 1, z1 = z0 + 1;
    auto clampi = [](int v) { return v < 0 ? 0 : (v > 127 ? 127 : v); };
    auto valid = [](int zi, int yi, int xi) -> bool {
        return ((unsigned)zi < 128u) && ((unsigned)yi < 128u) && ((unsigned)xi < 128u);
    };
    int xc0 = clampi(x0), xc1 = clampi(x1);
    int yc0 = clampi(y0), yc1 = clampi(y1);
    int zc0 = clampi(z0), zc1 = clampi(z1);
    int idx[8] = {
        (zc0 << 14) | (yc0 << 7) | xc0, (zc0 << 14) | (yc0 << 7) | xc1,
        (zc0 << 14) | (yc1 << 7) | xc0, (zc0 << 14) | (yc1 << 7) | xc1,
        (zc1 << 14) | (yc0 << 7) | xc0, (zc1 << 14) | (yc0 << 7) | xc1,
        (zc1 << 14) | (yc1 << 7) | xc0, (zc1 << 14) | (yc1 << 7) | xc1 };
    float v[8];
#pragma unroll
    for (int q = 0; q < 8; ++q) v[q] = (float)V[idx[q]];
    if (!valid(z0, y0, x0)) v[0] = 0.f;
    if (!valid(z0, y0, x1)) v[1] = 0.f;
    if (!valid(z0, y1, x0)) v[2] = 0.f;
    if (!valid(z0, y1, x1)) v[3] = 0.f;
    if (!valid(z1, y0, x0)) v[4] = 0.f;
    if (!valid(z1, y0, x1)) v[5] = 0.f;
    if (!valid(z1, y1, x0)) v[6] = 0.f;
    if (!valid(z1, y1, x1)) v[7] = 0.f;
    return v[0] * (1.f - tz) * (1.f - ty) * (1.f - tx) +
           v[1] * (1.f - tz) * (1.f - ty) * tx +
           v[2] * (1.f - tz) * ty * (1.f - tx) +
           v[3] * (1.f - tz) * ty * tx +
           v[4] * tz * (1.f - ty) * (1.f - tx) +
           v[5] * tz * (1.f - ty) * tx +
           v[6] * tz * ty * (1.f - tx) +
           v[7] * tz * ty * tx;
}

// fp-source grid-sample for the fallback path.
__device__ __forceinline__ float sample3d(const void* __restrict__ vol, int vbf,
                                          float cz, float cy, float cx) {
    float fx = (cx + 1.0f) * 64.0f - 0.5f;
    float fy = (cy + 1.0f) * 64.0f - 0.5f;
    float fz = (cz + 1.0f) * 64.0f - 0.5f;
    float x0f = floorf(fx), y0f = floorf(fy), z0f = floorf(fz);
    float tx = fx - x0f, ty = fy - y0f, tz = fz - z0f;
    int x0 = (int)x0f, y0 = (int)y0f, z0 = (int)z0f;
    int x1 = x0 + 1, y1 = y0 + 1, z1 = z0 + 1;
    auto clampi = [](int v) { return v < 0 ? 0 : (v > 127 ? 127 : v); };
    auto valid = [](int zi, int yi, int xi) -> bool {
        return ((unsigned)zi < 128u) && ((unsigned)yi < 128u) && ((unsigned)xi < 128u);
    };
    int xc0 = clampi(x0), xc1 = clampi(x1);
    int yc0 = clampi(y0), yc1 = clampi(y1);
    int zc0 = clampi(z0), zc1 = clampi(z1);
    int idx[8] = {
        (zc0 << 14) | (yc0 << 7) | xc0, (zc0 << 14) | (yc0 << 7) | xc1,
        (zc0 << 14) | (yc1 << 7) | xc0, (zc0 << 14) | (yc1 << 7) | xc1,
        (zc1 << 14) | (yc0 << 7) | xc0, (zc1 << 14) | (yc0 << 7) | xc1,
        (zc1 << 14) | (yc1 << 7) | xc0, (zc1 << 14) | (yc1 << 7) | xc1 };
    float v[8];
    if (vbf) {
        const __hip_bfloat16* V = (const __hip_bfloat16*)vol;
#pragma unroll
        for (int q = 0; q < 8; ++q) v[q] = bf2f(V[idx[q]]);
    } else {
        const float* V = (const float*)vol;
#pragma unroll
        for (int q = 0; q < 8; ++q) v[q] = V[idx[q]];
    }
    if (!valid(z0, y0, x0)) v[0] = 0.f;
    if (!valid(z0, y0, x1)) v[1] = 0.f;
    if (!valid(z0, y1, x0)) v[2] = 0.f;
    if (!valid(z0, y1, x1)) v[3] = 0.f;
    if (!valid(z1, y0, x0)) v[4] = 0.f;
    if (!valid(z1, y0, x1)) v[5] = 0.f;
    if (!valid(z1, y1, x0)) v[6] = 0.f;
    if (!valid(z1, y1, x1)) v[7] = 0.f;
    return v[0] * (1.f - tz) * (1.f - ty) * (1.f - tx) +
           v[1] * (1.f - tz) * (1.f - ty) * tx +
           v[2] * (1.f - tz) * ty * (1.f - tx) +
           v[3] * (1.f - tz) * ty * tx +
           v[4] * tz * (1.f - ty) * (1.f - tx) +
           v[5] * tz * (1.f - ty) * tx +
           v[6] * tz * ty * (1.f - tx) +
           v[7] * tz * ty * tx;
}

// ---------------------------------------------------------------------------
// Query: 4 pts/thread. Per point: 4 dwordx4 pair-table gathers + 8 u8 vol
// gathers = 12 scattered requests (was 16 in the R0/R2 46-us config).
// Working set 3.98 MB fits one XCD L2. Request-rate model predicts ~35 us.
// ---------------------------------------------------------------------------
__global__ __launch_bounds__(256) void query_kernel(
    const void* __restrict__ coords,
    const float* __restrict__ ws,
    float* __restrict__ out) {
    int t = blockIdx.x * 256 + threadIdx.x;   // quad-of-points index
    if (t >= NPTS / 4) return;

    const int* flags = (const int*)(ws + 1024);
    int cbf = flags[0];

    float y[4][3];
    if (cbf) {
        const u2* C2 = (const u2*)((const unsigned short*)coords + 12 * t);
        u2 ua = __builtin_nontemporal_load(C2);
        u2 ub = __builtin_nontemporal_load(C2 + 1);
        u2 uc = __builtin_nontemporal_load(C2 + 2);
        unsigned uu[6] = {ua.x, ua.y, ub.x, ub.y, uc.x, uc.y};
#pragma unroll
        for (int p = 0; p < 4; ++p)
#pragma unroll
            for (int d = 0; d < 3; ++d) {
                int k = 3 * p + d;
                unsigned h = uu[k >> 1];
                h = (k & 1) ? (h & 0xFFFF0000u) : (h << 16);
                y[p][d] = __builtin_bit_cast(float, h);
            }
    } else {
        const f4* C4 = (const f4*)((const float*)coords + 12 * t);
        f4 a = __builtin_nontemporal_load(C4);
        f4 b = __builtin_nontemporal_load(C4 + 1);
        f4 c = __builtin_nontemporal_load(C4 + 2);
        y[0][0] = a.x; y[0][1] = a.y; y[0][2] = a.z;
        y[1][0] = a.w; y[1][1] = b.x; y[1][2] = b.y;
        y[2][0] = b.z; y[2][1] = b.w; y[2][2] = c.x;
        y[3][0] = c.y; y[3][1] = c.z; y[3][2] = c.w;
    }

    auto cell = [](float tt, int* idx, float* f) {
        int v = (int)floorf(tt);
        v = v < 0 ? 0 : (v > TB - 2 ? TB - 2 : v);
        *idx = v; *f = tt - (float)v;
    };

    int bidx[4];
    float ff[4][3];
#pragma unroll
    for (int p = 0; p < 4; ++p) {
        float t0 = (y[p][0] + 1.0f) * TB_SCALE;
        float t1 = (y[p][1] + 1.0f) * TB_SCALE;
        float t2 = (y[p][2] + 1.0f) * TB_SCALE;
        int i0, i1, i2;
        cell(t0, &i0, &ff[p][0]);
        cell(t1, &i1, &ff[p][1]);
        cell(t2, &i2, &ff[p][2]);
        bidx[p] = (i0 * TB + i1) * TB + i2;
    }

    // Pair-table gathers: each entry = {node(i2), node(i2+1)} as 8 shorts.
    const s8v* E = (const s8v*)((const char*)ws + TBL_OFF_B);
    s8v ev[4][4];
#pragma unroll
    for (int p = 0; p < 4; ++p) {
        int b = bidx[p];
        ev[p][0] = E[b];                 // (i0  ,i1  ) -> c000|c001
        ev[p][1] = E[b + TB];            // (i0  ,i1+1) -> c010|c011
        ev[p][2] = E[b + TB2];           // (i0+1,i1  ) -> c100|c101
        ev[p][3] = E[b + TB2 + TB];      // (i0+1,i1+1) -> c110|c111
    }

    float c1v[4][3];
#pragma unroll
    for (int p = 0; p < 4; ++p) {
        float f0 = ff[p][0], f1 = ff[p][1], f2 = ff[p][2];
#pragma unroll
        for (int d = 0; d < 3; ++d) {
            float a00 = lerp1((float)ev[p][0][d], (float)ev[p][0][4 + d], f2);
            float a01 = lerp1((float)ev[p][1][d], (float)ev[p][1][4 + d], f2);
            float a10 = lerp1((float)ev[p][2][d], (float)ev[p][2][4 + d], f2);
            float a11 = lerp1((float)ev[p][3][d], (float)ev[p][3][4 + d], f2);
            c1v[p][d] = lerp1(lerp1(a00, a01, f1), lerp1(a10, a11, f1), f0) * QSI;
        }
    }

    // c1 out: 12 contiguous floats, 16B-aligned -> 3x dwordx4 plain stores.
    {
        float* dst = out + NPTS + 12 * t;
        f4 s0 = {c1v[0][0], c1v[0][1], c1v[0][2], c1v[1][0]};
        f4 s1 = {c1v[1][1], c1v[1][2], c1v[2][0], c1v[2][1]};
        f4 s2 = {c1v[2][2], c1v[3][0], c1v[3][1], c1v[3][2]};
        ((f4*)dst)[0] = s0;
        ((f4*)dst)[1] = s1;
        ((f4*)dst)[2] = s2;
    }

    const unsigned char* V8 = (const unsigned char*)ws + VOL8_OFF_B;
    f4 o;
#pragma unroll
    for (int p = 0; p < 4; ++p) {
        float sraw = sample3d_u8(V8, c1v[p][0], c1v[p][1], c1v[p][2]);
        o[p] = __builtin_fmaf(sraw, 2.0f / 255.0f, -1.0f);  // 2*(s/255) - 1
    }
    ((f4*)(out + 4 * t))[0] = o;
}

// Fallback direct kernel (R12 champion, 2 pts/thread) for small ws_size.
__global__ __launch_bounds__(64) void diffeo_kernel(
    const void* __restrict__ coords,
    const float* __restrict__ ws,
    const void* __restrict__ vol,
    float* __restrict__ out) {
    int t = blockIdx.x * 64 + threadIdx.x;   // pair index
    if (t >= NPTS / 2) return;

    const int* flags = (const int*)(ws + 1024);
    int cbf = flags[0];
    int vbf = flags[1];

    v2f y0, y1, y2;
    if (cbf) {
        const __hip_bfloat16* C = (const __hip_bfloat16*)coords;
        int b = 6 * t;
        y0.x = bf2f(C[b + 0]); y1.x = bf2f(C[b + 1]); y2.x = bf2f(C[b + 2]);
        y0.y = bf2f(C[b + 3]); y1.y = bf2f(C[b + 4]); y2.y = bf2f(C[b + 5]);
    } else {
        const float* C = (const float*)coords;
        int b = 6 * t;
        y0.x = C[b + 0]; y1.x = C[b + 1]; y2.x = C[b + 2];
        y0.y = C[b + 3]; y1.y = C[b + 4]; y2.y = C[b + 5];
    }

    integrate2(ws, y0, y1, y2);

    int b = 6 * t;
    out[NPTS + b + 0] = y0.x; out[NPTS + b + 1] = y1.x; out[NPTS + b + 2] = y2.x;
    out[NPTS + b + 3] = y0.y; out[NPTS + b + 4] = y1.y; out[NPTS + b + 5] = y2.y;

    float sA = sample3d(vol, vbf, y0.x, y1.x, y2.x);
    float sB = sample3d(vol, vbf, y0.y, y1.y, y2.y);
    out[2 * t + 0] = __builtin_fmaf(2.0f, sA, -1.0f);
    out[2 * t + 1] = __builtin_fmaf(2.0f, sB, -1.0f);
}

extern "C" void kernel_launch(void* const* d_in, const int* in_sizes, int n_in,
                              void* d_out, int out_size, void* d_ws, size_t ws_size,
                              hipStream_t stream) {
    const void* coords = d_in[0];
    const void* W1_0 = d_in[1];
    const void* b1_0 = d_in[2];
    const void* W2_0 = d_in[3];
    const void* b2_0 = d_in[4];
    const void* W1_1 = d_in[5];
    const void* b1_1 = d_in[6];
    const void* W2_1 = d_in[7];
    const void* b2_1 = d_in[8];
    const void* vol  = d_in[9];
    float* out = (float*)d_out;
    float* ws = (float*)d_ws;

    setup_kernel<<<1, 1024, 0, stream>>>(coords, W1_0, b1_0, W2_0, b2_0,
                                         W1_1, b1_1, W2_1, b2_1, vol, ws);
    if (ws_size >= WS_NEED) {
        unsigned char* vol8 = (unsigned char*)ws + VOL8_OFF_B;
        short* tbl = (short*)((char*)ws + TBL_OFF_B);
        conv_vol_kernel<<<VOL_N / 256, 256, 0, stream>>>(vol, ws, vol8);
        int node_pairs = (TB3 + 1) / 2;                  // 58825
        build_kernel<<<(node_pairs + 255) / 256, 256, 0, stream>>>(ws, tbl);
        query_kernel<<<NPTS / 1024, 256, 0, stream>>>(coords, ws, out);
    } else {
        diffeo_kernel<<<(NPTS / 2) / 64, 64, 0, stream>>>(coords, ws, vol, out);
    }
}

// Round 5
// 153.897 us; speedup vs baseline: 1.1293x; 1.0403x over previous
//
#include <hip/hip_runtime.h>
#include <hip/hip_bf16.h>

#define NPTS (96 * 96 * 96)   // 884736 points, divisible by 1024
#define HID 64
#define H_EFF 0.2f            // RK4 1 step/ODE — verified error << bf16 floor (R7/R8)

// L2-REQUEST MODEL (R0/R2/R3/R4 evidence): query is bound by distinct-L2-line
// touches/point (~8/cy/XCD saturation). Instructions & occupancy nearly free.
// This round: un-dup table (941 KB, i2-pair via two adjacent 8B loads -> 1
// line, MSHR-merged) + 128B-brick vol (4z*4y*8x: trilerp neighborhood =
// E[1.76] lines vs 4). Working set 0.94+2.1 = 3.04 MB << 4 MiB/XCD L2
// (R3 lesson: >4 MiB thrashes). Values bit-identical to R4 -> absmax same.
#define TB  49
#define TB2 (TB * TB)         // 2401
#define TB3 (TB * TB * TB)    // 117649
#define TB_SCALE 24.0f        // (y+1)*24 -> node index; spacing 1/24
#define TB_INV   0.0416666679f
#define QS   8192.0f          // int16 quant scale (err 6.1e-5; absmax 0.0195 R3/R4 PASS)
#define QSI  (1.0f / 8192.0f)
#define TBL_OFF_B 4128        // byte offset of node table in ws (8B entries)
#define TBL_BYTES ((size_t)TB3 * 8)          // 941192
#define VOLB_OFF_B 945408     // 4128+941192 rounded up to 128B boundary
#define VOL_N   (128 * 128 * 128)
#define WS_NEED ((size_t)VOLB_OFF_B + (size_t)VOL_N)

typedef float v2f __attribute__((ext_vector_type(2)));
typedef float f4  __attribute__((ext_vector_type(4)));
typedef unsigned u2 __attribute__((ext_vector_type(2)));
typedef short s4v __attribute__((ext_vector_type(4)));

__device__ __forceinline__ float bf2f(const __hip_bfloat16 v) {
    return __bfloat162float(v);
}
__device__ __forceinline__ v2f splat(float x) { v2f r; r.x = x; r.y = x; return r; }
__device__ __forceinline__ v2f vfma(v2f a, v2f b, v2f c) {
    return __builtin_elementwise_fma(a, b, c);
}
__device__ __forceinline__ float lerp1(float a, float b, float f) {
    return __builtin_fmaf(f, b - a, a);
}

// Brick address pieces: layout [bz:5][by:5][bx:4][z&3:2][y&3:2][x&7:3].
// Bit ranges are disjoint: px -> bits 0-2,7-10; py -> 3-4,11-15; pz -> 5-6,16-20.
__device__ __forceinline__ int bpx(int x) { return ((x >> 3) << 7) | (x & 7); }
__device__ __forceinline__ int bpy(int y) { return ((y >> 2) << 11) | ((y & 3) << 3); }
__device__ __forceinline__ int bpz(int z) { return ((z >> 2) << 16) | ((z & 3) << 5); }

// ---------------------------------------------------------------------------
// Setup: dtype detection + weight fold into ws[0..1024), flags at ws[1024..1026).
// W1' = K*W1, b1' = K*b1 (K=2*log2 e), W2' = -2*W2, b2'' = b2 + sum_j W2[j][k]
//   =>  out = b2'' + sum_j W2'_jk * rcp(1 + 2^pre')
// ---------------------------------------------------------------------------
__global__ void setup_kernel(
    const void* __restrict__ coords,
    const void* __restrict__ W1_0, const void* __restrict__ b1_0,
    const void* __restrict__ W2_0, const void* __restrict__ b2_0,
    const void* __restrict__ W1_1, const void* __restrict__ b1_1,
    const void* __restrict__ W2_1, const void* __restrict__ b2_1,
    const void* __restrict__ vol,
    float* __restrict__ ws) {
    __shared__ int sflags[3];
    int tid = threadIdx.x;
    if (tid < 64) {
        auto sane = [](const void* p, int i) -> bool {
            unsigned e = (((const unsigned short*)p)[i] >> 7) & 0xFFu;
            return e >= 97u && e <= 129u;
        };
        unsigned long long m;
        m = __ballot(sane(W1_0, tid));
        if (tid == 0) sflags[2] = (__popcll(m) >= 52) ? 1 : 0;
        m = __ballot(sane(coords, tid));
        if (tid == 0) sflags[0] = (__popcll(m) >= 52) ? 1 : 0;
        m = __ballot(sane(vol, tid));
        if (tid == 0) sflags[1] = (__popcll(m) >= 52) ? 1 : 0;
    }
    __syncthreads();
    int isbf = sflags[2];
    const float K = 2.88539008177792681472f;  // 2/ln(2)
    int ode = tid >> 9;
    int r = tid & 511;
    const void* W1 = ode ? W1_1 : W1_0;
    const void* b1 = ode ? b1_1 : b1_0;
    const void* W2 = ode ? W2_1 : W2_0;
    const void* b2 = ode ? b2_1 : b2_0;
    auto ld = [&](const void* p, int idx) -> float {
        return isbf ? bf2f(((const __hip_bfloat16*)p)[idx]) : ((const float*)p)[idx];
    };
    float v = 0.0f;
    if (r < 192)       v = K * ld(W1, r);
    else if (r < 256)  v = K * ld(b1, r - 192);
    else if (r < 448)  v = -2.0f * ld(W2, r - 256);
    else if (r < 451) {
        int k = r - 448;
        float s = ld(b2, k);
        for (int j = 0; j < HID; ++j) s += ld(W2, 3 * j + k);
        v = s;
    }
    ws[(ode << 9) + r] = v;
    if (tid < 2) ((int*)(ws + 1024))[tid] = sflags[tid];
}

// Quantize vol to uint8 and write in 128B-brick layout. Thread = bricked dest
// index (coalesced stores); source read is gather (8B-contiguous per 8 lanes).
__global__ __launch_bounds__(256) void conv_vol_kernel(
    const void* __restrict__ vol,
    const float* __restrict__ ws,
    unsigned char* __restrict__ volb) {
    int d = blockIdx.x * 256 + threadIdx.x;
    if (d >= VOL_N) return;
    int vbf = ((const int*)(ws + 1024))[1];
    int x = (((d >> 7) & 15) << 3) | (d & 7);
    int y = (((d >> 11) & 31) << 2) | ((d >> 3) & 3);
    int z = (((d >> 16) & 31) << 2) | ((d >> 5) & 3);
    int src = (z << 14) | (y << 7) | x;
    float v = vbf ? bf2f(((const __hip_bfloat16*)vol)[src]) : ((const float*)vol)[src];
    float q = __builtin_fmaf(v, 255.0f, 0.5f);
    q = q < 0.f ? 0.f : (q > 255.f ? 255.f : q);
    volb[d] = (unsigned char)q;
}

// MLP eval for a PAIR of points. Shared-rcp: one v_rcp of qx*qy recovers both
// reciprocals. q in [1, ~3000]; v_rcp rel err ~1e-7 (accuracy budget R10:
// c1 err must be <= ~2.3e-4; one-Newton bit-rcp at 3.6e-3 FAILED).
__device__ __forceinline__ void mlp_f2(const float* __restrict__ w,
                                       v2f y0, v2f y1, v2f y2,
                                       v2f& o0, v2f& o1, v2f& o2) {
    v2f a0 = splat(w[448]), a1 = splat(w[449]), a2 = splat(w[450]);
#pragma unroll 8
    for (int j = 0; j < HID; ++j) {
        v2f pre = vfma(y0, splat(w[j]),
                  vfma(y1, splat(w[64 + j]),
                  vfma(y2, splat(w[128 + j]), splat(w[192 + j]))));
        v2f e;
        e.x = __builtin_amdgcn_exp2f(pre.x);
        e.y = __builtin_amdgcn_exp2f(pre.y);
        v2f q = e + splat(1.0f);
        float rP = __builtin_amdgcn_rcpf(q.x * q.y);
        v2f r;
        r.x = q.y * rP;
        r.y = q.x * rP;
        a0 = vfma(r, splat(w[256 + 3 * j + 0]), a0);
        a1 = vfma(r, splat(w[256 + 3 * j + 1]), a1);
        a2 = vfma(r, splat(w[256 + 3 * j + 2]), a2);
    }
    o0 = a0; o1 = a1; o2 = a2;
}

// Full 2-ODE RK4 (1 step of h=0.2 each) for a pair of points, in-place.
__device__ __forceinline__ void integrate2(const float* __restrict__ ws,
                                           v2f& y0, v2f& y1, v2f& y2) {
    const float h = H_EFF;
#pragma unroll 1
    for (int ode = 0; ode < 2; ++ode) {
        const float* __restrict__ w = ws + (ode << 9);
        v2f k0 = splat(0.f), k1 = splat(0.f), k2 = splat(0.f);
        v2f s0 = splat(0.f), s1 = splat(0.f), s2 = splat(0.f);
#pragma unroll 1
        for (int e = 0; e < 4; ++e) {
            float ae = (e == 0) ? 0.0f : ((e == 3) ? h : 0.5f * h);
            float we = (e == 1 || e == 2) ? 2.0f : 1.0f;
            v2f aev = splat(ae), wev = splat(we);
            v2f f0, f1, f2;
            mlp_f2(w,
                   vfma(aev, k0, y0),
                   vfma(aev, k1, y1),
                   vfma(aev, k2, y2),
                   f0, f1, f2);
            k0 = f0; k1 = f1; k2 = f2;
            s0 = vfma(wev, k0, s0);
            s1 = vfma(wev, k1, s1);
            s2 = vfma(wev, k2, s2);
        }
        v2f h6 = splat(h / 6.0f);
        y0 = vfma(h6, s0, y0);
        y1 = vfma(h6, s1, y1);
        y2 = vfma(h6, s2, y2);
    }
}

// ---------------------------------------------------------------------------
// Table build: integrate the 49^3 lattice nodes (2 per thread, 256-thread
// blocks -> 920 waves). Un-duplicated: node n -> one 8B entry (4 shorts).
// ---------------------------------------------------------------------------
__global__ __launch_bounds__(256) void build_kernel(const float* __restrict__ ws,
                                                    s4v* __restrict__ tbl) {
    int t = blockIdx.x * 256 + threadIdx.x;   // node-pair index
    int nA = 2 * t;
    if (nA >= TB3) return;
    int nB = nA + 1;
    int nBc = nB < TB3 ? nB : (TB3 - 1);

    auto node_y = [](int n, float* a, float* b, float* c) {
        int i0 = n / TB2;
        int rem = n - i0 * TB2;
        int i1 = rem / TB;
        int i2 = rem - i1 * TB;
        *a = __builtin_fmaf((float)i0, TB_INV, -1.0f);
        *b = __builtin_fmaf((float)i1, TB_INV, -1.0f);
        *c = __builtin_fmaf((float)i2, TB_INV, -1.0f);
    };
    float ax, bx, cxv, ay, by, cyv;
    node_y(nA,  &ax, &bx, &cxv);
    node_y(nBc, &ay, &by, &cyv);
    v2f y0, y1, y2;
    y0.x = ax;  y1.x = bx;  y2.x = cxv;
    y0.y = ay;  y1.y = by;  y2.y = cyv;

    integrate2(ws, y0, y1, y2);

    auto quant = [](float v) -> short {
        float q = v * QS;
        q = q < -32767.f ? -32767.f : (q > 32767.f ? 32767.f : q);
        return (short)(int)rintf(q);
    };
    s4v qA = { quant(y0.x), quant(y1.x), quant(y2.x), 0 };
    s4v qB = { quant(y0.y), quant(y1.y), quant(y2.y), 0 };

    tbl[nA] = qA;
    if (nB < TB3) tbl[nB] = qB;
}

// fp-source grid-sample for the fallback path.
__device__ __forceinline__ float sample3d(const void* __restrict__ vol, int vbf,
                                          float cz, float cy, float cx) {
    float fx = (cx + 1.0f) * 64.0f - 0.5f;
    float fy = (cy + 1.0f) * 64.0f - 0.5f;
    float fz = (cz + 1.0f) * 64.0f - 0.5f;
    float x0f = floorf(fx), y0f = floorf(fy), z0f = floorf(fz);
    float tx = fx - x0f, ty = fy - y0f, tz = fz - z0f;
    int x0 = (int)x0f, y0 = (int)y0f, z0 = (int)z0f;
    int x1 = x0 + 1, y1 = y0 + 1, z1 = z0 + 1;
    auto clampi = [](int v) { return v < 0 ? 0 : (v > 127 ? 127 : v); };
    auto valid = [](int zi, int yi, int xi) -> bool {
        return ((unsigned)zi < 128u) && ((unsigned)yi < 128u) && ((unsigned)xi < 128u);
    };
    int xc0 = clampi(x0), xc1 = clampi(x1);
    int yc0 = clampi(y0), yc1 = clampi(y1);
    int zc0 = clampi(z0), zc1 = clampi(z1);
    int idx[8] = {
        (zc0 << 14) | (yc0 << 7) | xc0, (zc0 << 14) | (yc0 << 7) | xc1,
        (zc0 << 14) | (yc1 << 7) | xc0, (zc0 << 14) | (yc1 << 7) | xc1,
        (zc1 << 14) | (yc0 << 7) | xc0, (zc1 << 14) | (yc0 << 7) | xc1,
        (zc1 << 14) | (yc1 << 7) | xc0, (zc1 << 14) | (yc1 << 7) | xc1 };
    float v[8];
    if (vbf) {
        const __hip_bfloat16* V = (const __hip_bfloat16*)vol;
#pragma unroll
        for (int q = 0; q < 8; ++q) v[q] = bf2f(V[idx[q]]);
    } else {
        const float* V = (const float*)vol;
#pragma unroll
        for (int q = 0; q < 8; ++q) v[q] = V[idx[q]];
    }
    if (!valid(z0, y0, x0)) v[0] = 0.f;
    if (!valid(z0, y0, x1)) v[1] = 0.f;
    if (!valid(z0, y1, x0)) v[2] = 0.f;
    if (!valid(z0, y1, x1)) v[3] = 0.f;
    if (!valid(z1, y0, x0)) v[4] = 0.f;
    if (!valid(z1, y0, x1)) v[5] = 0.f;
    if (!valid(z1, y1, x0)) v[6] = 0.f;
    if (!valid(z1, y1, x1)) v[7] = 0.f;
    return v[0] * (1.f - tz) * (1.f - ty) * (1.f - tx) +
           v[1] * (1.f - tz) * (1.f - ty) * tx +
           v[2] * (1.f - tz) * ty * (1.f - tx) +
           v[3] * (1.f - tz) * ty * tx +
           v[4] * tz * (1.f - ty) * (1.f - tx) +
           v[5] * tz * (1.f - ty) * tx +
           v[6] * tz * ty * (1.f - tx) +
           v[7] * tz * ty * tx;
}

// ---------------------------------------------------------------------------
// Query: 4 pts/thread. Per point: 8x 8B table loads (i2-pairs share a line ->
// ~4 L2 line-requests) + 8 u8 bricked-vol loads (x/y/z pairs mostly share a
// 128B brick -> E[1.76] line-requests). Total ~6 unique lines vs 8 before.
// ---------------------------------------------------------------------------
__global__ __launch_bounds__(256) void query_kernel(
    const void* __restrict__ coords,
    const float* __restrict__ ws,
    float* __restrict__ out) {
    int t = blockIdx.x * 256 + threadIdx.x;   // quad-of-points index
    if (t >= NPTS / 4) return;

    const int* flags = (const int*)(ws + 1024);
    int cbf = flags[0];

    float y[4][3];
    if (cbf) {
        const u2* C2 = (const u2*)((const unsigned short*)coords + 12 * t);
        u2 ua = __builtin_nontemporal_load(C2);
        u2 ub = __builtin_nontemporal_load(C2 + 1);
        u2 uc = __builtin_nontemporal_load(C2 + 2);
        unsigned uu[6] = {ua.x, ua.y, ub.x, ub.y, uc.x, uc.y};
#pragma unroll
        for (int p = 0; p < 4; ++p)
#pragma unroll
            for (int d = 0; d < 3; ++d) {
                int k = 3 * p + d;
                unsigned h = uu[k >> 1];
                h = (k & 1) ? (h & 0xFFFF0000u) : (h << 16);
                y[p][d] = __builtin_bit_cast(float, h);
            }
    } else {
        const f4* C4 = (const f4*)((const float*)coords + 12 * t);
        f4 a = __builtin_nontemporal_load(C4);
        f4 b = __builtin_nontemporal_load(C4 + 1);
        f4 c = __builtin_nontemporal_load(C4 + 2);
        y[0][0] = a.x; y[0][1] = a.y; y[0][2] = a.z;
        y[1][0] = a.w; y[1][1] = b.x; y[1][2] = b.y;
        y[2][0] = b.z; y[2][1] = b.w; y[2][2] = c.x;
        y[3][0] = c.y; y[3][1] = c.z; y[3][2] = c.w;
    }

    auto cell = [](float tt, int* idx, float* f) {
        int v = (int)floorf(tt);
        v = v < 0 ? 0 : (v > TB - 2 ? TB - 2 : v);
        *idx = v; *f = tt - (float)v;
    };

    int bidx[4];
    float ff[4][3];
#pragma unroll
    for (int p = 0; p < 4; ++p) {
        float t0 = (y[p][0] + 1.0f) * TB_SCALE;
        float t1 = (y[p][1] + 1.0f) * TB_SCALE;
        float t2 = (y[p][2] + 1.0f) * TB_SCALE;
        int i0, i1, i2;
        cell(t0, &i0, &ff[p][0]);
        cell(t1, &i1, &ff[p][1]);
        cell(t2, &i2, &ff[p][2]);
        bidx[p] = (i0 * TB + i1) * TB + i2;
    }

    // Un-dup table: 8B entries; lo = node(i2), hi = node(i2+1) via adjacent
    // loads (same 16B region -> one L2 line-request after MSHR merge).
    const s4v* T = (const s4v*)((const char*)ws + TBL_OFF_B);
    s4v ev[4][8];
#pragma unroll
    for (int p = 0; p < 4; ++p) {
        int b = bidx[p];
        ev[p][0] = T[b];                 ev[p][1] = T[b + 1];
        ev[p][2] = T[b + TB];            ev[p][3] = T[b + TB + 1];
        ev[p][4] = T[b + TB2];           ev[p][5] = T[b + TB2 + 1];
        ev[p][6] = T[b + TB2 + TB];      ev[p][7] = T[b + TB2 + TB + 1];
    }

    float c1v[4][3];
#pragma unroll
    for (int p = 0; p < 4; ++p) {
        float f0 = ff[p][0], f1 = ff[p][1], f2 = ff[p][2];
#pragma unroll
        for (int d = 0; d < 3; ++d) {
            float a00 = lerp1((float)ev[p][0][d], (float)ev[p][1][d], f2);
            float a01 = lerp1((float)ev[p][2][d], (float)ev[p][3][d], f2);
            float a10 = lerp1((float)ev[p][4][d], (float)ev[p][5][d], f2);
            float a11 = lerp1((float)ev[p][6][d], (float)ev[p][7][d], f2);
            c1v[p][d] = lerp1(lerp1(a00, a01, f1), lerp1(a10, a11, f1), f0) * QSI;
        }
    }

    // c1 out: 12 contiguous floats, 16B-aligned -> 3x dwordx4 plain stores.
    {
        float* dst = out + NPTS + 12 * t;
        f4 s0 = {c1v[0][0], c1v[0][1], c1v[0][2], c1v[1][0]};
        f4 s1 = {c1v[1][1], c1v[1][2], c1v[2][0], c1v[2][1]};
        f4 s2 = {c1v[2][2], c1v[3][0], c1v[3][1], c1v[3][2]};
        ((f4*)dst)[0] = s0;
        ((f4*)dst)[1] = s1;
        ((f4*)dst)[2] = s2;
    }

    // Bricked-vol sample: 8 u8 gathers per point, mostly same 128B brick.
    const unsigned char* VB = (const unsigned char*)ws + VOLB_OFF_B;
    f4 o;
#pragma unroll
    for (int p = 0; p < 4; ++p) {
        // Reference reorder: c1[2]->x, c1[1]->y, c1[0]->z.
        float fx = (c1v[p][2] + 1.0f) * 64.0f - 0.5f;
        float fy = (c1v[p][1] + 1.0f) * 64.0f - 0.5f;
        float fz = (c1v[p][0] + 1.0f) * 64.0f - 0.5f;
        float x0f = floorf(fx), y0f = floorf(fy), z0f = floorf(fz);
        float tx = fx - x0f, ty = fy - y0f, tz = fz - z0f;
        int x0 = (int)x0f, y0 = (int)y0f, z0 = (int)z0f;
        int x1 = x0 + 1, y1 = y0 + 1, z1 = z0 + 1;
        auto clampi = [](int v) { return v < 0 ? 0 : (v > 127 ? 127 : v); };
        auto valid = [](int zi, int yi, int xi) -> bool {
            return ((unsigned)zi < 128u) && ((unsigned)yi < 128u) &&
                   ((unsigned)xi < 128u);
        };
        int px0 = bpx(clampi(x0)), px1 = bpx(clampi(x1));
        int py0 = bpy(clampi(y0)), py1 = bpy(clampi(y1));
        int pz0 = bpz(clampi(z0)), pz1 = bpz(clampi(z1));
        float v[8];
        v[0] = (float)VB[pz0 | py0 | px0];
        v[1] = (float)VB[pz0 | py0 | px1];
        v[2] = (float)VB[pz0 | py1 | px0];
        v[3] = (float)VB[pz0 | py1 | px1];
        v[4] = (float)VB[pz1 | py0 | px0];
        v[5] = (float)VB[pz1 | py0 | px1];
        v[6] = (float)VB[pz1 | py1 | px0];
        v[7] = (float)VB[pz1 | py1 | px1];
        if (!valid(z0, y0, x0)) v[0] = 0.f;
        if (!valid(z0, y0, x1)) v[1] = 0.f;
        if (!valid(z0, y1, x0)) v[2] = 0.f;
        if (!valid(z0, y1, x1)) v[3] = 0.f;
        if (!valid(z1, y0, x0)) v[4] = 0.f;
        if (!valid(z1, y0, x1)) v[5] = 0.f;
        if (!valid(z1, y1, x0)) v[6] = 0.f;
        if (!valid(z1, y1, x1)) v[7] = 0.f;
        float sraw =
            v[0] * (1.f - tz) * (1.f - ty) * (1.f - tx) +
            v[1] * (1.f - tz) * (1.f - ty) * tx +
            v[2] * (1.f - tz) * ty * (1.f - tx) +
            v[3] * (1.f - tz) * ty * tx +
            v[4] * tz * (1.f - ty) * (1.f - tx) +
            v[5] * tz * (1.f - ty) * tx +
            v[6] * tz * ty * (1.f - tx) +
            v[7] * tz * ty * tx;
        o[p] = __builtin_fmaf(sraw, 2.0f / 255.0f, -1.0f);  // 2*(s/255) - 1
    }
    ((f4*)(out + 4 * t))[0] = o;
}

// Fallback direct kernel (R12 champion, 2 pts/thread) for small ws_size.
__global__ __launch_bounds__(64) void diffeo_kernel(
    const void* __restrict__ coords,
    const float* __restrict__ ws,
    const void* __restrict__ vol,
    float* __restrict__ out) {
    int t = blockIdx.x * 64 + threadIdx.x;   // pair index
    if (t >= NPTS / 2) return;

    const int* flags = (const int*)(ws + 1024);
    int cbf = flags[0];
    int vbf = flags[1];

    v2f y0, y1, y2;
    if (cbf) {
        const __hip_bfloat16* C = (const __hip_bfloat16*)coords;
        int b = 6 * t;
        y0.x = bf2f(C[b + 0]); y1.x = bf2f(C[b + 1]); y2.x = bf2f(C[b + 2]);
        y0.y = bf2f(C[b + 3]); y1.y = bf2f(C[b + 4]); y2.y = bf2f(C[b + 5]);
    } else {
        const float* C = (const float*)coords;
        int b = 6 * t;
        y0.x = C[b + 0]; y1.x = C[b + 1]; y2.x = C[b + 2];
        y0.y = C[b + 3]; y1.y = C[b + 4]; y2.y = C[b + 5];
    }

    integrate2(ws, y0, y1, y2);

    int b = 6 * t;
    out[NPTS + b + 0] = y0.x; out[NPTS + b + 1] = y1.x; out[NPTS + b + 2] = y2.x;
    out[NPTS + b + 3] = y0.y; out[NPTS + b + 4] = y1.y; out[NPTS + b + 5] = y2.y;

    float sA = sample3d(vol, vbf, y0.x, y1.x, y2.x);
    float sB = sample3d(vol, vbf, y0.y, y1.y, y2.y);
    out[2 * t + 0] = __builtin_fmaf(2.0f, sA, -1.0f);
    out[2 * t + 1] = __builtin_fmaf(2.0f, sB, -1.0f);
}

extern "C" void kernel_launch(void* const* d_in, const int* in_sizes, int n_in,
                              void* d_out, int out_size, void* d_ws, size_t ws_size,
                              hipStream_t stream) {
    const void* coords = d_in[0];
    const void* W1_0 = d_in[1];
    const void* b1_0 = d_in[2];
    const void* W2_0 = d_in[3];
    const void* b2_0 = d_in[4];
    const void* W1_1 = d_in[5];
    const void* b1_1 = d_in[6];
    const void* W2_1 = d_in[7];
    const void* b2_1 = d_in[8];
    const void* vol  = d_in[9];
    float* out = (float*)d_out;
    float* ws = (float*)d_ws;

    setup_kernel<<<1, 1024, 0, stream>>>(coords, W1_0, b1_0, W2_0, b2_0,
                                         W1_1, b1_1, W2_1, b2_1, vol, ws);
    if (ws_size >= WS_NEED) {
        unsigned char* volb = (unsigned char*)ws + VOLB_OFF_B;
        s4v* tbl = (s4v*)((char*)ws + TBL_OFF_B);
        conv_vol_kernel<<<VOL_N / 256, 256, 0, stream>>>(vol, ws, volb);
        int node_pairs = (TB3 + 1) / 2;                  // 58825
        build_kernel<<<(node_pairs + 255) / 256, 256, 0, stream>>>(ws, tbl);
        query_kernel<<<NPTS / 1024, 256, 0, stream>>>(coords, ws, out);
    } else {
        diffeo_kernel<<<(NPTS / 2) / 64, 64, 0, stream>>>(coords, ws, vol, out);
    }
}

// Round 6
// 147.287 us; speedup vs baseline: 1.1800x; 1.0449x over previous
//
#include <hip/hip_runtime.h>
#include <hip/hip_bf16.h>

#define NPTS (96 * 96 * 96)   // 884736 points
#define HID 64
#define H_EFF 0.2f            // RK4 1 step/ODE — verified error << bf16 floor

// Table: int16-quantized 8B node entries (un-dup, R5). Brick vol (R5).
// Working set 0.94+2.1 MB < 4 MiB/XCD L2 (R3 lesson). Values bit-identical
// to R5 except 64-term MLP sum is now combined as (lo32)+(hi32) per lane
// pair — reorder wiggle ~1e-6, inside the 6.1e-5 quant bin.
// BUILD (R5 post-mortem): was ~95us at 0.9 waves/SIMD, latency-starved.
// Now: lane-PAIR per point-pair, j-split 32/32, shfl_xor combine ->
// 1838 waves (1.8/SIMD) + LDS-packed float4 weight rows (2x ds_read_b128/j).
#define TB  49
#define TB2 (TB * TB)         // 2401
#define TB3 (TB * TB * TB)    // 117649
#define TB_SCALE 24.0f
#define TB_INV   0.0416666679f
#define QS   8192.0f
#define QSI  (1.0f / 8192.0f)
#define TBL_OFF_B 4128
#define VOLB_OFF_B 945408     // 128B-aligned, after 941192B table
#define VOL_N   (128 * 128 * 128)
#define WS_NEED ((size_t)VOLB_OFF_B + (size_t)VOL_N)

#define BUILD_BLOCKS 460      // ceil((TB3+1)/256) threads: 2 lanes per point-pair
#define CONV_BLOCKS  1024     // VOL_N / (256*8)

typedef float v2f __attribute__((ext_vector_type(2)));
typedef float f4  __attribute__((ext_vector_type(4)));
typedef unsigned u2 __attribute__((ext_vector_type(2)));
typedef unsigned u4 __attribute__((ext_vector_type(4)));
typedef short s4v __attribute__((ext_vector_type(4)));

__device__ __forceinline__ float bf2f(const __hip_bfloat16 v) {
    return __bfloat162float(v);
}
__device__ __forceinline__ v2f splat(float x) { v2f r; r.x = x; r.y = x; return r; }
__device__ __forceinline__ v2f vfma(v2f a, v2f b, v2f c) {
    return __builtin_elementwise_fma(a, b, c);
}
__device__ __forceinline__ float lerp1(float a, float b, float f) {
    return __builtin_fmaf(f, b - a, a);
}

// Brick address pieces: [bz:5][by:5][bx:4][z&3:2][y&3:2][x&7:3].
__device__ __forceinline__ int bpx(int x) { return ((x >> 3) << 7) | (x & 7); }
__device__ __forceinline__ int bpy(int y) { return ((y >> 2) << 11) | ((y & 3) << 3); }
__device__ __forceinline__ int bpz(int z) { return ((z >> 2) << 16) | ((z & 3) << 5); }

__device__ __forceinline__ int detect_bf16(const void* p, int tid, int* sflag) {
    if (tid < 64) {
        unsigned e = (((const unsigned short*)p)[tid] >> 7) & 0xFFu;
        unsigned long long m = __ballot(e >= 97u && e <= 129u);
        if (tid == 0) *sflag = (__popcll(m) >= 52) ? 1 : 0;
    }
    __syncthreads();
    return *sflag;
}

// ---------------------------------------------------------------------------
// setup_kernel: FALLBACK-PATH ONLY (diffeo needs folded weights + flags in ws).
// ---------------------------------------------------------------------------
__global__ void setup_kernel(
    const void* __restrict__ coords,
    const void* __restrict__ W1_0, const void* __restrict__ b1_0,
    const void* __restrict__ W2_0, const void* __restrict__ b2_0,
    const void* __restrict__ W1_1, const void* __restrict__ b1_1,
    const void* __restrict__ W2_1, const void* __restrict__ b2_1,
    const void* __restrict__ vol,
    float* __restrict__ ws) {
    __shared__ int sflags[3];
    int tid = threadIdx.x;
    if (tid < 64) {
        auto sane = [](const void* p, int i) -> bool {
            unsigned e = (((const unsigned short*)p)[i] >> 7) & 0xFFu;
            return e >= 97u && e <= 129u;
        };
        unsigned long long m;
        m = __ballot(sane(W1_0, tid));
        if (tid == 0) sflags[2] = (__popcll(m) >= 52) ? 1 : 0;
        m = __ballot(sane(coords, tid));
        if (tid == 0) sflags[0] = (__popcll(m) >= 52) ? 1 : 0;
        m = __ballot(sane(vol, tid));
        if (tid == 0) sflags[1] = (__popcll(m) >= 52) ? 1 : 0;
    }
    __syncthreads();
    int isbf = sflags[2];
    const float K = 2.88539008177792681472f;  // 2/ln(2)
    int ode = tid >> 9;
    int r = tid & 511;
    const void* W1 = ode ? W1_1 : W1_0;
    const void* b1 = ode ? b1_1 : b1_0;
    const void* W2 = ode ? W2_1 : W2_0;
    const void* b2 = ode ? b2_1 : b2_0;
    auto ld = [&](const void* p, int idx) -> float {
        return isbf ? bf2f(((const __hip_bfloat16*)p)[idx]) : ((const float*)p)[idx];
    };
    float v = 0.0f;
    if (r < 192)       v = K * ld(W1, r);
    else if (r < 256)  v = K * ld(b1, r - 192);
    else if (r < 448)  v = -2.0f * ld(W2, r - 256);
    else if (r < 451) {
        int k = r - 448;
        float s = ld(b2, k);
        for (int j = 0; j < HID; ++j) s += ld(W2, 3 * j + k);
        v = s;
    }
    ws[(ode << 9) + r] = v;
    if (tid < 2) ((int*)(ws + 1024))[tid] = sflags[tid];
}

// Pair-point MLP (fallback path, lane-uniform weights from global ws).
__device__ __forceinline__ void mlp_f2(const float* __restrict__ w,
                                       v2f y0, v2f y1, v2f y2,
                                       v2f& o0, v2f& o1, v2f& o2) {
    v2f a0 = splat(w[448]), a1 = splat(w[449]), a2 = splat(w[450]);
#pragma unroll 8
    for (int j = 0; j < HID; ++j) {
        v2f pre = vfma(y0, splat(w[j]),
                  vfma(y1, splat(w[64 + j]),
                  vfma(y2, splat(w[128 + j]), splat(w[192 + j]))));
        v2f e;
        e.x = __builtin_amdgcn_exp2f(pre.x);
        e.y = __builtin_amdgcn_exp2f(pre.y);
        v2f q = e + splat(1.0f);
        float rP = __builtin_amdgcn_rcpf(q.x * q.y);
        v2f r;
        r.x = q.y * rP;
        r.y = q.x * rP;
        a0 = vfma(r, splat(w[256 + 3 * j + 0]), a0);
        a1 = vfma(r, splat(w[256 + 3 * j + 1]), a1);
        a2 = vfma(r, splat(w[256 + 3 * j + 2]), a2);
    }
    o0 = a0; o1 = a1; o2 = a2;
}

__device__ __forceinline__ void integrate2(const float* __restrict__ ws,
                                           v2f& y0, v2f& y1, v2f& y2) {
    const float h = H_EFF;
#pragma unroll 1
    for (int ode = 0; ode < 2; ++ode) {
        const float* __restrict__ w = ws + (ode << 9);
        v2f k0 = splat(0.f), k1 = splat(0.f), k2 = splat(0.f);
        v2f s0 = splat(0.f), s1 = splat(0.f), s2 = splat(0.f);
#pragma unroll 1
        for (int e = 0; e < 4; ++e) {
            float ae = (e == 0) ? 0.0f : ((e == 3) ? h : 0.5f * h);
            float we = (e == 1 || e == 2) ? 2.0f : 1.0f;
            v2f aev = splat(ae), wev = splat(we);
            v2f f0, f1, f2;
            mlp_f2(w, vfma(aev, k0, y0), vfma(aev, k1, y1), vfma(aev, k2, y2),
                   f0, f1, f2);
            k0 = f0; k1 = f1; k2 = f2;
            s0 = vfma(wev, k0, s0);
            s1 = vfma(wev, k1, s1);
            s2 = vfma(wev, k2, s2);
        }
        v2f h6 = splat(h / 6.0f);
        y0 = vfma(h6, s0, y0);
        y1 = vfma(h6, s1, y1);
        y2 = vfma(h6, s2, y2);
    }
}

// ---------------------------------------------------------------------------
// prep_kernel: fused build (blocks < BUILD_BLOCKS) + vol conversion (rest).
// Build: lane-pair (2k,2k+1) handles one point-pair as v2f; even lane sums
// j in [0,32), odd lane [32,64); shfl_xor(1) combine (bit-identical both
// lanes: one commutative add). Weights folded per block into LDS float4 rows.
// ---------------------------------------------------------------------------
__global__ __launch_bounds__(256) void prep_kernel(
    const void* __restrict__ W1_0, const void* __restrict__ b1_0,
    const void* __restrict__ W2_0, const void* __restrict__ b2_0,
    const void* __restrict__ W1_1, const void* __restrict__ b1_1,
    const void* __restrict__ W2_1, const void* __restrict__ b2_1,
    const void* __restrict__ vol,
    float* __restrict__ ws) {
    int tid = threadIdx.x;
    if (blockIdx.x < BUILD_BLOCKS) {
        __shared__ int sflag;
        __shared__ f4 sw1[2][64];     // {K*W1[0][j], K*W1[1][j], K*W1[2][j], K*b1[j]}
        __shared__ f4 sw2[2][64];     // {-2*W2[j][0], -2*W2[j][1], -2*W2[j][2], 0}
        __shared__ float sb2[2][4];   // b2'' per ode
        int isbf = detect_bf16(W1_0, tid, &sflag);
        const float K = 2.88539008177792681472f;
        auto ld = [&](const void* p, int idx) -> float {
            return isbf ? bf2f(((const __hip_bfloat16*)p)[idx]) : ((const float*)p)[idx];
        };
        {
            int ode = (tid >> 6) & 1;
            int j = tid & 63;
            const void* W1 = ode ? W1_1 : W1_0;
            const void* b1 = ode ? b1_1 : b1_0;
            const void* W2 = ode ? W2_1 : W2_0;
            if (tid < 128) {
                f4 c = { K * ld(W1, j), K * ld(W1, 64 + j),
                         K * ld(W1, 128 + j), K * ld(b1, j) };
                sw1[ode][j] = c;
            } else {
                f4 c = { -2.f * ld(W2, 3 * j + 0), -2.f * ld(W2, 3 * j + 1),
                         -2.f * ld(W2, 3 * j + 2), 0.f };
                sw2[ode][j] = c;
            }
            if (tid < 6) {
                int o = tid / 3, k = tid - 3 * o;
                const void* W2o = o ? W2_1 : W2_0;
                const void* b2o = o ? b2_1 : b2_0;
                float s = ld(b2o, k);
                for (int jj = 0; jj < HID; ++jj) s += ld(W2o, 3 * jj + k);
                sb2[o][k] = s;
            }
        }
        __syncthreads();

        int gtid = blockIdx.x * 256 + tid;
        int lp = gtid >> 1;       // point-pair index
        int h  = gtid & 1;        // j-half
        int nA = 2 * lp;
        if (nA >= TB3) return;
        int nB = nA + 1;
        int nBc = nB < TB3 ? nB : (TB3 - 1);

        auto node_y = [](int n, float* a, float* b, float* c) {
            int i0 = n / TB2;
            int rem = n - i0 * TB2;
            int i1 = rem / TB;
            int i2 = rem - i1 * TB;
            *a = __builtin_fmaf((float)i0, TB_INV, -1.0f);
            *b = __builtin_fmaf((float)i1, TB_INV, -1.0f);
            *c = __builtin_fmaf((float)i2, TB_INV, -1.0f);
        };
        float ax, bx, cxv, ay, by, cyv;
        node_y(nA,  &ax, &bx, &cxv);
        node_y(nBc, &ay, &by, &cyv);
        v2f y0, y1, y2;
        y0.x = ax;  y1.x = bx;  y2.x = cxv;
        y0.y = ay;  y1.y = by;  y2.y = cyv;

        const float hh = H_EFF;
        int jbase = h << 5;
#pragma unroll 1
        for (int ode = 0; ode < 2; ++ode) {
            const f4* __restrict__ w1 = sw1[ode];
            const f4* __restrict__ w2 = sw2[ode];
            v2f b2v0 = h ? splat(0.f) : splat(sb2[ode][0]);
            v2f b2v1 = h ? splat(0.f) : splat(sb2[ode][1]);
            v2f b2v2 = h ? splat(0.f) : splat(sb2[ode][2]);
            v2f k0 = splat(0.f), k1 = splat(0.f), k2 = splat(0.f);
            v2f s0 = splat(0.f), s1 = splat(0.f), s2 = splat(0.f);
#pragma unroll 1
            for (int e = 0; e < 4; ++e) {
                float ae = (e == 0) ? 0.0f : ((e == 3) ? hh : 0.5f * hh);
                float we = (e == 1 || e == 2) ? 2.0f : 1.0f;
                v2f aev = splat(ae), wev = splat(we);
                v2f z0 = vfma(aev, k0, y0);
                v2f z1 = vfma(aev, k1, y1);
                v2f z2 = vfma(aev, k2, y2);
                v2f a0 = b2v0, a1 = b2v1, a2 = b2v2;
#pragma unroll 8
                for (int jj = 0; jj < 32; ++jj) {
                    f4 c1 = w1[jbase + jj];
                    v2f pre = vfma(z0, splat(c1.x),
                              vfma(z1, splat(c1.y),
                              vfma(z2, splat(c1.z), splat(c1.w))));
                    v2f ev;
                    ev.x = __builtin_amdgcn_exp2f(pre.x);
                    ev.y = __builtin_amdgcn_exp2f(pre.y);
                    v2f q = ev + splat(1.0f);
                    float rP = __builtin_amdgcn_rcpf(q.x * q.y);
                    v2f r;
                    r.x = q.y * rP;
                    r.y = q.x * rP;
                    f4 c2 = w2[jbase + jj];
                    a0 = vfma(r, splat(c2.x), a0);
                    a1 = vfma(r, splat(c2.y), a1);
                    a2 = vfma(r, splat(c2.z), a2);
                }
                // combine lane-pair halves (both lanes end with full sum)
                v2f t;
                t.x = __shfl_xor(a0.x, 1); t.y = __shfl_xor(a0.y, 1); a0 += t;
                t.x = __shfl_xor(a1.x, 1); t.y = __shfl_xor(a1.y, 1); a1 += t;
                t.x = __shfl_xor(a2.x, 1); t.y = __shfl_xor(a2.y, 1); a2 += t;
                k0 = a0; k1 = a1; k2 = a2;
                s0 = vfma(wev, k0, s0);
                s1 = vfma(wev, k1, s1);
                s2 = vfma(wev, k2, s2);
            }
            v2f h6 = splat(hh / 6.0f);
            y0 = vfma(h6, s0, y0);
            y1 = vfma(h6, s1, y1);
            y2 = vfma(h6, s2, y2);
        }

        if (h == 0) {
            auto quant = [](float v) -> short {
                float q = v * QS;
                q = q < -32767.f ? -32767.f : (q > 32767.f ? 32767.f : q);
                return (short)(int)rintf(q);
            };
            s4v* T = (s4v*)((char*)ws + TBL_OFF_B);
            s4v qA = { quant(y0.x), quant(y1.x), quant(y2.x), 0 };
            T[nA] = qA;
            if (nB < TB3) {
                s4v qB = { quant(y0.y), quant(y1.y), quant(y2.y), 0 };
                T[nB] = qB;
            }
        }
    } else {
        // ------- conv: quantize vol to u8 in 128B-brick layout, 8 vox/thread
        __shared__ int svf;
        int vbf = detect_bf16(vol, tid, &svf);
        int g = (blockIdx.x - BUILD_BLOCKS) * 256 + tid;
        int d0 = g * 8;                        // 8 consecutive bricked bytes
        int x0 = ((d0 >> 7) & 15) << 3;        // d0&7 == 0
        int yy = (((d0 >> 11) & 31) << 2) | ((d0 >> 3) & 3);
        int zz = (((d0 >> 16) & 31) << 2) | ((d0 >> 5) & 3);
        int src = (zz << 14) | (yy << 7) | x0; // 8 consecutive source voxels
        float v[8];
        if (vbf) {
            u4 w = *(const u4*)((const unsigned short*)vol + src);
#pragma unroll
            for (int i = 0; i < 4; ++i) {
                unsigned ww = w[i];
                v[2 * i + 0] = __builtin_bit_cast(float, ww << 16);
                v[2 * i + 1] = __builtin_bit_cast(float, ww & 0xFFFF0000u);
            }
        } else {
            const f4* F = (const f4*)((const float*)vol + src);
            f4 A = F[0], B = F[1];
            v[0] = A.x; v[1] = A.y; v[2] = A.z; v[3] = A.w;
            v[4] = B.x; v[5] = B.y; v[6] = B.z; v[7] = B.w;
        }
        unsigned q[8];
#pragma unroll
        for (int i = 0; i < 8; ++i) {
            float qq = __builtin_fmaf(v[i], 255.0f, 0.5f);
            qq = qq < 0.f ? 0.f : (qq > 255.f ? 255.f : qq);
            q[i] = (unsigned)qq;
        }
        u2 pk;
        pk.x = q[0] | (q[1] << 8) | (q[2] << 16) | (q[3] << 24);
        pk.y = q[4] | (q[5] << 8) | (q[6] << 16) | (q[7] << 24);
        *(u2*)((unsigned char*)ws + VOLB_OFF_B + d0) = pk;
    }
}

// fp-source grid-sample for the fallback path.
__device__ __forceinline__ float sample3d(const void* __restrict__ vol, int vbf,
                                          float cz, float cy, float cx) {
    float fx = (cx + 1.0f) * 64.0f - 0.5f;
    float fy = (cy + 1.0f) * 64.0f - 0.5f;
    float fz = (cz + 1.0f) * 64.0f - 0.5f;
    float x0f = floorf(fx), y0f = floorf(fy), z0f = floorf(fz);
    float tx = fx - x0f, ty = fy - y0f, tz = fz - z0f;
    int x0 = (int)x0f, y0 = (int)y0f, z0 = (int)z0f;
    int x1 = x0 + 1, y1 = y0 + 1, z1 = z0 + 1;
    auto clampi = [](int v) { return v < 0 ? 0 : (v > 127 ? 127 : v); };
    auto valid = [](int zi, int yi, int xi) -> bool {
        return ((unsigned)zi < 128u) && ((unsigned)yi < 128u) && ((unsigned)xi < 128u);
    };
    int xc0 = clampi(x0), xc1 = clampi(x1);
    int yc0 = clampi(y0), yc1 = clampi(y1);
    int zc0 = clampi(z0), zc1 = clampi(z1);
    int idx[8] = {
        (zc0 << 14) | (yc0 << 7) | xc0, (zc0 << 14) | (yc0 << 7) | xc1,
        (zc0 << 14) | (yc1 << 7) | xc0, (zc0 << 14) | (yc1 << 7) | xc1,
        (zc1 << 14) | (yc0 << 7) | xc0, (zc1 << 14) | (yc0 << 7) | xc1,
        (zc1 << 14) | (yc1 << 7) | xc0, (zc1 << 14) | (yc1 << 7) | xc1 };
    float v[8];
    if (vbf) {
        const __hip_bfloat16* V = (const __hip_bfloat16*)vol;
#pragma unroll
        for (int q = 0; q < 8; ++q) v[q] = bf2f(V[idx[q]]);
    } else {
        const float* V = (const float*)vol;
#pragma unroll
        for (int q = 0; q < 8; ++q) v[q] = V[idx[q]];
    }
    if (!valid(z0, y0, x0)) v[0] = 0.f;
    if (!valid(z0, y0, x1)) v[1] = 0.f;
    if (!valid(z0, y1, x0)) v[2] = 0.f;
    if (!valid(z0, y1, x1)) v[3] = 0.f;
    if (!valid(z1, y0, x0)) v[4] = 0.f;
    if (!valid(z1, y0, x1)) v[5] = 0.f;
    if (!valid(z1, y1, x0)) v[6] = 0.f;
    if (!valid(z1, y1, x1)) v[7] = 0.f;
    return v[0] * (1.f - tz) * (1.f - ty) * (1.f - tx) +
           v[1] * (1.f - tz) * (1.f - ty) * tx +
           v[2] * (1.f - tz) * ty * (1.f - tx) +
           v[3] * (1.f - tz) * ty * tx +
           v[4] * tz * (1.f - ty) * (1.f - tx) +
           v[5] * tz * (1.f - ty) * tx +
           v[6] * tz * ty * (1.f - tx) +
           v[7] * tz * ty * tx;
}

// ---------------------------------------------------------------------------
// Query (R5 structure, unchanged gather pattern) + per-block cbf self-detect.
// ---------------------------------------------------------------------------
__global__ __launch_bounds__(256) void query_kernel(
    const void* __restrict__ coords,
    const float* __restrict__ ws,
    float* __restrict__ out) {
    __shared__ int scf;
    int cbf = detect_bf16(coords, threadIdx.x, &scf);
    int t = blockIdx.x * 256 + threadIdx.x;   // quad-of-points index
    if (t >= NPTS / 4) return;

    float y[4][3];
    if (cbf) {
        const u2* C2 = (const u2*)((const unsigned short*)coords + 12 * t);
        u2 ua = __builtin_nontemporal_load(C2);
        u2 ub = __builtin_nontemporal_load(C2 + 1);
        u2 uc = __builtin_nontemporal_load(C2 + 2);
        unsigned uu[6] = {ua.x, ua.y, ub.x, ub.y, uc.x, uc.y};
#pragma unroll
        for (int p = 0; p < 4; ++p)
#pragma unroll
            for (int d = 0; d < 3; ++d) {
                int k = 3 * p + d;
                unsigned h = uu[k >> 1];
                h = (k & 1) ? (h & 0xFFFF0000u) : (h << 16);
                y[p][d] = __builtin_bit_cast(float, h);
            }
    } else {
        const f4* C4 = (const f4*)((const float*)coords + 12 * t);
        f4 a = __builtin_nontemporal_load(C4);
        f4 b = __builtin_nontemporal_load(C4 + 1);
        f4 c = __builtin_nontemporal_load(C4 + 2);
        y[0][0] = a.x; y[0][1] = a.y; y[0][2] = a.z;
        y[1][0] = a.w; y[1][1] = b.x; y[1][2] = b.y;
        y[2][0] = b.z; y[2][1] = b.w; y[2][2] = c.x;
        y[3][0] = c.y; y[3][1] = c.z; y[3][2] = c.w;
    }

    auto cell = [](float tt, int* idx, float* f) {
        int v = (int)floorf(tt);
        v = v < 0 ? 0 : (v > TB - 2 ? TB - 2 : v);
        *idx = v; *f = tt - (float)v;
    };

    int bidx[4];
    float ff[4][3];
#pragma unroll
    for (int p = 0; p < 4; ++p) {
        float t0 = (y[p][0] + 1.0f) * TB_SCALE;
        float t1 = (y[p][1] + 1.0f) * TB_SCALE;
        float t2 = (y[p][2] + 1.0f) * TB_SCALE;
        int i0, i1, i2;
        cell(t0, &i0, &ff[p][0]);
        cell(t1, &i1, &ff[p][1]);
        cell(t2, &i2, &ff[p][2]);
        bidx[p] = (i0 * TB + i1) * TB + i2;
    }

    const s4v* T = (const s4v*)((const char*)ws + TBL_OFF_B);
    s4v ev[4][8];
#pragma unroll
    for (int p = 0; p < 4; ++p) {
        int b = bidx[p];
        ev[p][0] = T[b];                 ev[p][1] = T[b + 1];
        ev[p][2] = T[b + TB];            ev[p][3] = T[b + TB + 1];
        ev[p][4] = T[b + TB2];           ev[p][5] = T[b + TB2 + 1];
        ev[p][6] = T[b + TB2 + TB];      ev[p][7] = T[b + TB2 + TB + 1];
    }

    float c1v[4][3];
#pragma unroll
    for (int p = 0; p < 4; ++p) {
        float f0 = ff[p][0], f1 = ff[p][1], f2 = ff[p][2];
#pragma unroll
        for (int d = 0; d < 3; ++d) {
            float a00 = lerp1((float)ev[p][0][d], (float)ev[p][1][d], f2);
            float a01 = lerp1((float)ev[p][2][d], (float)ev[p][3][d], f2);
            float a10 = lerp1((float)ev[p][4][d], (float)ev[p][5][d], f2);
            float a11 = lerp1((float)ev[p][6][d], (float)ev[p][7][d], f2);
            c1v[p][d] = lerp1(lerp1(a00, a01, f1), lerp1(a10, a11, f1), f0) * QSI;
        }
    }

    {
        float* dst = out + NPTS + 12 * t;
        f4 s0 = {c1v[0][0], c1v[0][1], c1v[0][2], c1v[1][0]};
        f4 s1 = {c1v[1][1], c1v[1][2], c1v[2][0], c1v[2][1]};
        f4 s2 = {c1v[2][2], c1v[3][0], c1v[3][1], c1v[3][2]};
        ((f4*)dst)[0] = s0;
        ((f4*)dst)[1] = s1;
        ((f4*)dst)[2] = s2;
    }

    const unsigned char* VB = (const unsigned char*)ws + VOLB_OFF_B;
    f4 o;
#pragma unroll
    for (int p = 0; p < 4; ++p) {
        float fx = (c1v[p][2] + 1.0f) * 64.0f - 0.5f;
        float fy = (c1v[p][1] + 1.0f) * 64.0f - 0.5f;
        float fz = (c1v[p][0] + 1.0f) * 64.0f - 0.5f;
        float x0f = floorf(fx), y0f = floorf(fy), z0f = floorf(fz);
        float tx = fx - x0f, ty = fy - y0f, tz = fz - z0f;
        int x0 = (int)x0f, y0 = (int)y0f, z0 = (int)z0f;
        int x1 = x0 + 1, y1 = y0 + 1, z1 = z0 + 1;
        auto clampi = [](int v) { return v < 0 ? 0 : (v > 127 ? 127 : v); };
        auto valid = [](int zi, int yi, int xi) -> bool {
            return ((unsigned)zi < 128u) && ((unsigned)yi < 128u) &&
                   ((unsigned)xi < 128u);
        };
        int px0 = bpx(clampi(x0)), px1 = bpx(clampi(x1));
        int py0 = bpy(clampi(y0)), py1 = bpy(clampi(y1));
        int pz0 = bpz(clampi(z0)), pz1 = bpz(clampi(z1));
        float v[8];
        v[0] = (float)VB[pz0 | py0 | px0];
        v[1] = (float)VB[pz0 | py0 | px1];
        v[2] = (float)VB[pz0 | py1 | px0];
        v[3] = (float)VB[pz0 | py1 | px1];
        v[4] = (float)VB[pz1 | py0 | px0];
        v[5] = (float)VB[pz1 | py0 | px1];
        v[6] = (float)VB[pz1 | py1 | px0];
        v[7] = (float)VB[pz1 | py1 | px1];
        if (!valid(z0, y0, x0)) v[0] = 0.f;
        if (!valid(z0, y0, x1)) v[1] = 0.f;
        if (!valid(z0, y1, x0)) v[2] = 0.f;
        if (!valid(z0, y1, x1)) v[3] = 0.f;
        if (!valid(z1, y0, x0)) v[4] = 0.f;
        if (!valid(z1, y0, x1)) v[5] = 0.f;
        if (!valid(z1, y1, x0)) v[6] = 0.f;
        if (!valid(z1, y1, x1)) v[7] = 0.f;
        float sraw =
            v[0] * (1.f - tz) * (1.f - ty) * (1.f - tx) +
            v[1] * (1.f - tz) * (1.f - ty) * tx +
            v[2] * (1.f - tz) * ty * (1.f - tx) +
            v[3] * (1.f - tz) * ty * tx +
            v[4] * tz * (1.f - ty) * (1.f - tx) +
            v[5] * tz * (1.f - ty) * tx +
            v[6] * tz * ty * (1.f - tx) +
            v[7] * tz * ty * tx;
        o[p] = __builtin_fmaf(sraw, 2.0f / 255.0f, -1.0f);
    }
    ((f4*)(out + 4 * t))[0] = o;
}

// Fallback direct kernel (2 pts/thread) for small ws_size.
__global__ __launch_bounds__(64) void diffeo_kernel(
    const void* __restrict__ coords,
    const float* __restrict__ ws,
    const void* __restrict__ vol,
    float* __restrict__ out) {
    int t = blockIdx.x * 64 + threadIdx.x;   // pair index
    if (t >= NPTS / 2) return;

    const int* flags = (const int*)(ws + 1024);
    int cbf = flags[0];
    int vbf = flags[1];

    v2f y0, y1, y2;
    if (cbf) {
        const __hip_bfloat16* C = (const __hip_bfloat16*)coords;
        int b = 6 * t;
        y0.x = bf2f(C[b + 0]); y1.x = bf2f(C[b + 1]); y2.x = bf2f(C[b + 2]);
        y0.y = bf2f(C[b + 3]); y1.y = bf2f(C[b + 4]); y2.y = bf2f(C[b + 5]);
    } else {
        const float* C = (const float*)coords;
        int b = 6 * t;
        y0.x = C[b + 0]; y1.x = C[b + 1]; y2.x = C[b + 2];
        y0.y = C[b + 3]; y1.y = C[b + 4]; y2.y = C[b + 5];
    }

    integrate2(ws, y0, y1, y2);

    int b = 6 * t;
    out[NPTS + b + 0] = y0.x; out[NPTS + b + 1] = y1.x; out[NPTS + b + 2] = y2.x;
    out[NPTS + b + 3] = y0.y; out[NPTS + b + 4] = y1.y; out[NPTS + b + 5] = y2.y;

    float sA = sample3d(vol, vbf, y0.x, y1.x, y2.x);
    float sB = sample3d(vol, vbf, y0.y, y1.y, y2.y);
    out[2 * t + 0] = __builtin_fmaf(2.0f, sA, -1.0f);
    out[2 * t + 1] = __builtin_fmaf(2.0f, sB, -1.0f);
}

extern "C" void kernel_launch(void* const* d_in, const int* in_sizes, int n_in,
                              void* d_out, int out_size, void* d_ws, size_t ws_size,
                              hipStream_t stream) {
    const void* coords = d_in[0];
    const void* W1_0 = d_in[1];
    const void* b1_0 = d_in[2];
    const void* W2_0 = d_in[3];
    const void* b2_0 = d_in[4];
    const void* W1_1 = d_in[5];
    const void* b1_1 = d_in[6];
    const void* W2_1 = d_in[7];
    const void* b2_1 = d_in[8];
    const void* vol  = d_in[9];
    float* out = (float*)d_out;
    float* ws = (float*)d_ws;

    if (ws_size >= WS_NEED) {
        prep_kernel<<<BUILD_BLOCKS + CONV_BLOCKS, 256, 0, stream>>>(
            W1_0, b1_0, W2_0, b2_0, W1_1, b1_1, W2_1, b2_1, vol, ws);
        query_kernel<<<NPTS / 1024, 256, 0, stream>>>(coords, ws, out);
    } else {
        setup_kernel<<<1, 1024, 0, stream>>>(coords, W1_0, b1_0, W2_0, b2_0,
                                             W1_1, b1_1, W2_1, b2_1, vol, ws);
        diffeo_kernel<<<(NPTS / 2) / 64, 64, 0, stream>>>(coords, ws, vol, out);
    }
}